// Round 2
// baseline (783.199 us; speedup 1.0000x reference)
//
#include <hip/hip_runtime.h>
#include <math.h>

#define NNODES 262144      // B*N
#define NEDGE  2097152     // NNODES*DEG
#define NB     256         // graphs
#define NPG    1024        // nodes per graph
#define EPG    8192        // edges per graph
#define DF     128         // feature dim

typedef unsigned short u16;
typedef unsigned int   u32;
typedef __attribute__((ext_vector_type(8))) short  short8;   // 8 x bf16 (4 VGPRs)
typedef __attribute__((ext_vector_type(4))) float  floatx4;  // MFMA accumulator

static constexpr int K1 = 820, K2 = 656, K3 = 525;

// ---- bf16 helpers (manual, RTNE) ----
__device__ inline float bflo(u32 u) { union { u32 i; float f; } c; c.i = u << 16;          return c.f; }
__device__ inline float bfhi(u32 u) { union { u32 i; float f; } c; c.i = u & 0xffff0000u;  return c.f; }
__device__ inline u32   f2bf(float f) {
  union { float f; u32 i; } c; c.f = f;
  const u32 r = c.i + 0x7fffu + ((c.i >> 16) & 1u);
  return r >> 16;
}
__device__ inline void acc8(float* b, uint4 v) {
  b[0] += bflo(v.x); b[1] += bfhi(v.x);
  b[2] += bflo(v.y); b[3] += bfhi(v.y);
  b[4] += bflo(v.z); b[5] += bfhi(v.z);
  b[6] += bflo(v.w); b[7] += bfhi(v.w);
}
__device__ inline uint4 pack8(const float* s, float k) {
  uint4 o;
  o.x = f2bf(s[0] * k) | (f2bf(s[1] * k) << 16);
  o.y = f2bf(s[2] * k) | (f2bf(s[3] * k) << 16);
  o.z = f2bf(s[4] * k) | (f2bf(s[5] * k) << 16);
  o.w = f2bf(s[6] * k) | (f2bf(s[7] * k) << 16);
  return o;
}

// ---------------- CSR build (1024 thr): counting sort by dst + deg/keep init ----
// Also emits a per-graph degree-sorted node permutation (perm): agg_k assigns
// thread t node perm[t] so all 64 lanes of a wave walk near-identical edge
// counts (kills the ~2.1x exec-mask inflation from Poisson(8) in-degrees).
__global__ __launch_bounds__(1024) void build_csr_k(
    const int* __restrict__ ei, int* __restrict__ csr_src,
    int* __restrict__ row_off, int* __restrict__ row_cnt,
    float* __restrict__ degf, float* __restrict__ keep,
    int* __restrict__ perm)
{
  __shared__ int cnt[NPG];
  __shared__ int roff[NPG];
  __shared__ int wsum[NPG];
  __shared__ int hist[64];
  __shared__ int hoff[64];
  const int b = blockIdx.x, t = threadIdx.x;   // t in 0..1023
  const int* src = ei;
  const int* dst = ei + NEDGE;
  const int e0 = b * EPG;
  cnt[t] = 0;
  __syncthreads();
  for (int e = t; e < EPG; e += 1024) atomicAdd(&cnt[dst[e0 + e] & (NPG - 1)], 1);
  __syncthreads();
  const int v = cnt[t];
  wsum[t] = v;
  __syncthreads();
  for (int off = 1; off < NPG; off <<= 1) {
    const int u = (t >= off) ? wsum[t - off] : 0;
    __syncthreads();
    wsum[t] += u;
    __syncthreads();
  }
  const int base = wsum[t] - v;    // exclusive prefix
  roff[t] = base;
  const int n = b * NPG + t;
  row_off[n] = base;
  row_cnt[n] = v;
  degf[n]    = (float)v;           // layer-1 deg = full in-degree
  keep[n]    = 1.0f;
  if (t < 64) hist[t] = 0;
  __syncthreads();
  for (int e = t; e < EPG; e += 1024) {
    const int dl = dst[e0 + e] & (NPG - 1);
    const int pos = atomicAdd(&roff[dl], 1);
    csr_src[e0 + pos] = src[e0 + e];   // store GLOBAL src node id
  }
  // ---- degree-sorted permutation (counting sort over clamped degree) ----
  const int bkt = (v < 63) ? v : 63;
  atomicAdd(&hist[bkt], 1);
  __syncthreads();
  if (t == 0) {
    int s = 0;
#pragma unroll 1
    for (int i = 0; i < 64; ++i) { const int h = hist[i]; hoff[i] = s; s += h; }
  }
  __syncthreads();
  const int pp = atomicAdd(&hoff[bkt], 1);
  perm[b * NPG + pp] = t;
}

// ---------------- Embedding gather (f32 -> bf16, unscaled) + fac init -----------
__global__ __launch_bounds__(256) void gather_k(
    const int* __restrict__ x_ids, const float* __restrict__ emb,
    u16* __restrict__ x0, float* __restrict__ fac)
{
  const int gid = blockIdx.x * 256 + threadIdx.x;  // NNODES*16 threads
  const int n = gid >> 4, c = gid & 15;
  const int id = x_ids[n];
  const float4 v0 = *(const float4*)(emb + (size_t)id * DF + c * 8);
  const float4 v1 = *(const float4*)(emb + (size_t)id * DF + c * 8 + 4);
  uint4 pk;
  pk.x = f2bf(v0.x) | (f2bf(v0.y) << 16);
  pk.y = f2bf(v0.z) | (f2bf(v0.w) << 16);
  pk.z = f2bf(v1.x) | (f2bf(v1.y) << 16);
  pk.w = f2bf(v1.z) | (f2bf(v1.w) << 16);
  *(uint4*)(x0 + (size_t)n * DF + c * 8) = pk;
  if (c == 0) fac[n] = 1.0f;
}

// ---- Weight convert into SWIZZLED fragment order -------------------------------
// wF[l][f=ct*8+ks][lane][j] = wT[n=ct*16+(lane&15)][k=ks*32+(lane>>4)*8+j]
// where wT[n][k] = k<128 ? Wl[k][n] : Wr[k-128][n].  One wave per (l,f).
// NOTE: A- and B-fragment lane mappings of mfma_16x16x32 are identical, so this
// layout serves as either operand (gemm_k v4 uses it as the *A* operand).
__global__ __launch_bounds__(64) void wcvt_k(
    const float* __restrict__ Wl1, const float* __restrict__ Wr1,
    const float* __restrict__ Wl2, const float* __restrict__ Wr2,
    const float* __restrict__ Wl3, const float* __restrict__ Wr3,
    u16* __restrict__ wF)
{
  const int f = blockIdx.x & 63, l = blockIdx.x >> 6;
  const int lane = threadIdx.x;
  const int ct = f >> 3, ks = f & 7;
  const int n = ct * 16 + (lane & 15);
  const int k0 = ks * 32 + (lane >> 4) * 8;
  const float* Wl = (l == 0) ? Wl1 : (l == 1) ? Wl2 : Wl3;
  const float* Wr = (l == 0) ? Wr1 : (l == 1) ? Wr2 : Wr3;
  u16 o[8];
#pragma unroll
  for (int j = 0; j < 8; ++j) {
    const int k = k0 + j;
    const float v = (k < 128) ? Wl[k * 128 + n] : Wr[(k - 128) * 128 + n];
    o[j] = (u16)f2bf(v);
  }
  uint4 pk;
  pk.x = (u32)o[0] | ((u32)o[1] << 16);
  pk.y = (u32)o[2] | ((u32)o[3] << 16);
  pk.z = (u32)o[4] | ((u32)o[5] << 16);
  pk.w = (u32)o[6] | ((u32)o[7] << 16);
  *(uint4*)(wF + (((size_t)l * 64 + f) * 64 + lane) * 8) = pk;
}

// ---- Aggregation v4: LDS-staged gather, degree-sorted thread->node map ---------
__global__ __launch_bounds__(1024) void agg_k(
    const u16* __restrict__ xprev, const float* __restrict__ fac,
    const float* __restrict__ deg,
    const int* __restrict__ csr_src, const int* __restrict__ row_off,
    const int* __restrict__ row_cnt, const int* __restrict__ perm,
    u16* __restrict__ aggb)
{
  __shared__ u32 xl[16384];          // 64 KB: 1024 rows x 16 dwords (32 bf16)
  const int t = threadIdx.x;
  const int bi = blockIdx.x;         // 1024 = 256 graphs x 4 quarters
  const int g  = (bi & 7) + 8 * (bi >> 5);     // XCD swizzle
  const int qt = (bi >> 3) & 3;
  const int n  = g * NPG + t;
  // ---- stage (scaled, swizzled) ----
  {
    const float fr = fac[n];
    const uint4* src = (const uint4*)(xprev + (size_t)n * DF + qt * 32);
    u32* dst = xl + t * 16;
    const int sw = (t & 3) << 2;
#pragma unroll
    for (int j = 0; j < 4; ++j) {
      const uint4 v = src[j];
      uint4 o;
      o.x = f2bf(bflo(v.x) * fr) | (f2bf(bfhi(v.x) * fr) << 16);
      o.y = f2bf(bflo(v.y) * fr) | (f2bf(bfhi(v.y) * fr) << 16);
      o.z = f2bf(bflo(v.z) * fr) | (f2bf(bfhi(v.z) * fr) << 16);
      o.w = f2bf(bflo(v.w) * fr) | (f2bf(bfhi(v.w) * fr) << 16);
      *(uint4*)(dst + ((j << 2) ^ sw)) = o;
    }
  }
  const int m  = perm[n];            // node this thread aggregates
  const int nm = g * NPG + m;
  __syncthreads();
  // ---- gather-sum from LDS ----
  const int cnt = row_cnt[nm];
  const int* ep = csr_src + g * EPG + row_off[nm];
  float b[32];
#pragma unroll
  for (int j = 0; j < 32; ++j) b[j] = 0.0f;
  int e = 0;
  for (; e + 2 <= cnt; e += 2) {
    const int s0 = ep[e] & (NPG - 1), s1 = ep[e + 1] & (NPG - 1);
    const u32* r0 = xl + s0 * 16; const int w0 = (s0 & 3) << 2;
    const u32* r1 = xl + s1 * 16; const int w1 = (s1 & 3) << 2;
    const uint4 A0 = *(const uint4*)(r0 + (0  ^ w0));
    const uint4 A1 = *(const uint4*)(r0 + (4  ^ w0));
    const uint4 A2 = *(const uint4*)(r0 + (8  ^ w0));
    const uint4 A3 = *(const uint4*)(r0 + (12 ^ w0));
    const uint4 B0 = *(const uint4*)(r1 + (0  ^ w1));
    const uint4 B1 = *(const uint4*)(r1 + (4  ^ w1));
    const uint4 B2 = *(const uint4*)(r1 + (8  ^ w1));
    const uint4 B3 = *(const uint4*)(r1 + (12 ^ w1));
    acc8(b + 0, A0); acc8(b + 8, A1); acc8(b + 16, A2); acc8(b + 24, A3);
    acc8(b + 0, B0); acc8(b + 8, B1); acc8(b + 16, B2); acc8(b + 24, B3);
  }
  if (e < cnt) {
    const int s0 = ep[e] & (NPG - 1);
    const u32* r0 = xl + s0 * 16; const int w0 = (s0 & 3) << 2;
    const uint4 A0 = *(const uint4*)(r0 + (0  ^ w0));
    const uint4 A1 = *(const uint4*)(r0 + (4  ^ w0));
    const uint4 A2 = *(const uint4*)(r0 + (8  ^ w0));
    const uint4 A3 = *(const uint4*)(r0 + (12 ^ w0));
    acc8(b + 0, A0); acc8(b + 8, A1); acc8(b + 16, A2); acc8(b + 24, A3);
  }
  const float inv = 1.0f / fmaxf(deg[nm], 1.0f);
  uint4* op = (uint4*)(aggb + (size_t)nm * DF + qt * 32);
  op[0] = pack8(b + 0,  inv);
  op[1] = pack8(b + 8,  inv);
  op[2] = pack8(b + 16, inv);
  op[3] = pack8(b + 24, inv);
}

// ---- MFMA GEMM v4: operand-swapped (W as A-frag), split accumulators -----------
// D[feature][node] = mfma(W, x): each lane holds 4 consecutive features of one
// node -> direct uint2 stores, no LDS strip. aL = agg@Wl, aR = x@Wr; fac folded
// post-MFMA (removes the per-tile F->bf16(fac*x) conversion chain entirely).
// One barrier per tile: only race is the ch-pair sharing rows (in-place output).
__global__ __launch_bounds__(512) void gemm_k(
    u16* __restrict__ G, const u16* __restrict__ F,
    const float* __restrict__ fac,
    const u16* __restrict__ wF, const float* __restrict__ bl,
    const float* __restrict__ p, float* __restrict__ score)
{
  __shared__ float sc[256][2];
  const int t = threadIdx.x;
  const int bi = blockIdx.x;           // 1024 = 256 graphs x 4
  const int g   = (bi & 7) + 8 * (bi >> 5);
  const int tpg = (bi >> 3) & 3;
  const int n0  = g * NPG + tpg * 256;
  const int wv = t >> 6, lane = t & 63;
  const int rg = wv >> 1, ch = wv & 1;
  const int lr = lane & 15, quad = lane >> 4;

  // weights as MFMA *A* operand, held in registers for the whole kernel
  short8 bf[4][8];
#pragma unroll
  for (int ct = 0; ct < 4; ++ct)
#pragma unroll
    for (int ks = 0; ks < 8; ++ks) {
      const int f = (ch * 4 + ct) * 8 + ks;
      bf[ct][ks] = *(const short8*)(wF + ((size_t)f * 64 + lane) * 8);
    }
  // per-lane bias / score-weight for features fb = ch*64+ct*16+quad*4 .. +3
  float4 bn4[4], pn4[4];
#pragma unroll
  for (int ct = 0; ct < 4; ++ct) {
    const int fb = ch * 64 + ct * 16 + quad * 4;
    bn4[ct] = *(const float4*)(bl + fb);
    pn4[ct] = *(const float4*)(p + fb);
  }

#pragma unroll 1
  for (int tl = 0; tl < 4; ++tl) {
    const int rbase = n0 + rg * 64 + tl * 16;
    const int row = rbase + lr;          // this lane's node (output col)
    short8 ag[4], ax[4];
#pragma unroll
    for (int ks = 0; ks < 4; ++ks) {
      ag[ks] = *(const short8*)(G + (size_t)row * DF + ks * 32 + quad * 8);
      ax[ks] = *(const short8*)(F + (size_t)row * DF + ks * 32 + quad * 8);
    }
    const float fr = fac[row];
    floatx4 aL[4], aR[4];
#pragma unroll
    for (int ct = 0; ct < 4; ++ct) {
      aL[ct] = (floatx4){0.f, 0.f, 0.f, 0.f};
      aR[ct] = (floatx4){0.f, 0.f, 0.f, 0.f};
    }
#pragma unroll
    for (int ks = 0; ks < 4; ++ks)
#pragma unroll
      for (int ct = 0; ct < 4; ++ct) {
        aL[ct] = __builtin_amdgcn_mfma_f32_16x16x32_bf16(bf[ct][ks],     ag[ks], aL[ct], 0, 0, 0);
        aR[ct] = __builtin_amdgcn_mfma_f32_16x16x32_bf16(bf[ct][ks + 4], ax[ks], aR[ct], 0, 0, 0);
      }
    float si = 0.0f;
    u32 pk[4][2];
#pragma unroll
    for (int ct = 0; ct < 4; ++ct) {
      float v0 = fmaxf(aL[ct][0] + fr * aR[ct][0] + bn4[ct].x, 0.0f);
      float v1 = fmaxf(aL[ct][1] + fr * aR[ct][1] + bn4[ct].y, 0.0f);
      float v2 = fmaxf(aL[ct][2] + fr * aR[ct][2] + bn4[ct].z, 0.0f);
      float v3 = fmaxf(aL[ct][3] + fr * aR[ct][3] + bn4[ct].w, 0.0f);
      si += v0 * pn4[ct].x + v1 * pn4[ct].y + v2 * pn4[ct].z + v3 * pn4[ct].w;
      pk[ct][0] = f2bf(v0) | (f2bf(v1) << 16);
      pk[ct][1] = f2bf(v2) | (f2bf(v3) << 16);
    }
    si += __shfl_xor(si, 16, 64);
    si += __shfl_xor(si, 32, 64);
    if (lane < 16) sc[rg * 64 + tl * 16 + lr][ch] = si;
    __syncthreads();   // partner (ch) wave's reads of this tile are done
#pragma unroll
    for (int ct = 0; ct < 4; ++ct) {
      uint2 st; st.x = pk[ct][0]; st.y = pk[ct][1];
      *(uint2*)(G + (size_t)row * DF + ch * 64 + ct * 16 + quad * 4) = st;
    }
  }
  // sc fully written before the last in-loop barrier -> no extra barrier needed
  if (t < 256) score[n0 + t] = sc[t][0] + sc[t][1];
}

// ---- Per-graph top-k rank (exact argsort semantics) + edge-parallel next-deg ---
__global__ __launch_bounds__(1024) void rank_k(
    const float* __restrict__ score, const float* __restrict__ p,
    const int* __restrict__ ei,
    float* __restrict__ keep, float* __restrict__ fac,
    float* __restrict__ degN, int K, int next)
{
  __shared__ float s_lds[NPG];
  __shared__ float kfl[NPG];
  __shared__ float deg_l[NPG];
  const int b = blockIdx.x, t = threadIdx.x;
  float ssq = 0.0f;
  for (int d = 0; d < DF; ++d) ssq += p[d] * p[d];
  const float inv_pn = 1.0f / sqrtf(ssq);
  const float NEG = -__builtin_huge_valf();
  {
    const int n = b * NPG + t;
    s_lds[t] = (keep[n] > 0.5f) ? score[n] : NEG;
    deg_l[t] = 0.0f;
  }
  __syncthreads();
  const float si = s_lds[t];
  int rk = 0;
  for (int j = 0; j < NPG; ++j) {
    const float sj = s_lds[j];
    rk += (sj > si) || ((sj == si) && (j < t));
  }
  const bool kp = rk < K;          // implies previously-active (inactive = -inf)
  const int n = b * NPG + t;
  keep[n] = kp ? 1.0f : 0.0f;
  kfl[t]  = kp ? 1.0f : 0.0f;
  fac[n]  = kp ? tanhf(si * inv_pn) : 0.0f;
  __syncthreads();
  if (next) {
    const int e0 = b * EPG;
    for (int e = t; e < EPG; e += 1024) {
      const int sl = ei[e0 + e] & (NPG - 1);
      const int dl = ei[NEDGE + e0 + e] & (NPG - 1);
      atomicAdd(&deg_l[dl], kfl[sl]);
    }
    __syncthreads();
    degN[n] = deg_l[t];
  }
}

// ---- Parallel masked readout: 8 blocks/graph (reads unscaled xn, applies fac) --
__global__ __launch_bounds__(256) void readout_k(
    const u16* __restrict__ xn, const float* __restrict__ fac,
    const float* __restrict__ keep, float* __restrict__ xlp)
{
  __shared__ float mxA[256], mxB[256], smA[256], smB[256];
  const int blk = blockIdx.x, b = blk >> 3, pr = blk & 7, t = threadIdx.x;
  const int d = t & 63, rq = t >> 6;
  const float NEG = -__builtin_huge_valf();
  float mx0 = NEG, mx1 = NEG, sm0 = 0.0f, sm1 = 0.0f;
  for (int j = 0; j < 32; ++j) {
    const int n = b * NPG + pr * 128 + rq + j * 4;
    const float kf = keep[n];
    const float f  = fac[n];
    const u32 u = *(const u32*)(xn + (size_t)n * DF + d * 2);
    const float v0 = bflo(u) * f, v1 = bfhi(u) * f;
    if (kf > 0.5f) {
      mx0 = fmaxf(mx0, v0); mx1 = fmaxf(mx1, v1);
      sm0 += v0; sm1 += v1;
    }
  }
  mxA[t] = mx0; mxB[t] = mx1; smA[t] = sm0; smB[t] = sm1;
  __syncthreads();
  if (t < 64) {
    float m0 = mxA[t], m1 = mxB[t], s0 = smA[t], s1 = smB[t];
#pragma unroll
    for (int qq = 1; qq < 4; ++qq) {
      m0 = fmaxf(m0, mxA[qq * 64 + t]); m1 = fmaxf(m1, mxB[qq * 64 + t]);
      s0 += smA[qq * 64 + t];           s1 += smB[qq * 64 + t];
    }
    float* o = xlp + (size_t)blk * 256;
    o[2 * t]           = m0;
    o[2 * t + 1]       = m1;
    o[128 + 2 * t]     = s0;
    o[128 + 2 * t + 1] = s1;
  }
}

// ---------------- Final MLP head, one block per graph ----------------
__global__ __launch_bounds__(256) void mlp_k(
    const float* __restrict__ xlp,
    const float* __restrict__ W1, const float* __restrict__ b1,
    const float* __restrict__ W2, const float* __restrict__ b2,
    const float* __restrict__ W3, const float* __restrict__ b3,
    float* __restrict__ out)
{
  __shared__ float h0[256];
  __shared__ float h1[128];
  __shared__ float h2[64];
  const int b = blockIdx.x, t = threadIdx.x;
  const float invK[3] = {1.0f / (float)K1, 1.0f / (float)K2, 1.0f / (float)K3};
  float v = 0.0f;
#pragma unroll
  for (int l = 0; l < 3; ++l) {
    const float* base = xlp + ((size_t)l * NB * 8 + (size_t)b * 8) * 256;
    if (t < 128) {
      float m = base[t];
#pragma unroll
      for (int pr = 1; pr < 8; ++pr) m = fmaxf(m, base[pr * 256 + t]);
      v += m;
    } else {
      float s = 0.0f;
#pragma unroll
      for (int pr = 0; pr < 8; ++pr) s += base[pr * 256 + t];
      v += s * invK[l];
    }
  }
  h0[t] = v;
  __syncthreads();
  if (t < 128) {
    float a = b1[t];
    for (int k = 0; k < 256; ++k) a += h0[k] * W1[k * 128 + t];
    h1[t] = fmaxf(a, 0.0f);
  }
  __syncthreads();
  if (t < 64) {
    float a = b2[t];
    for (int k = 0; k < 128; ++k) a += h1[k] * W2[k * 64 + t];
    h2[t] = fmaxf(a, 0.0f);
  }
  __syncthreads();
  if (t < 64) {
    float vv = h2[t] * W3[t];
#pragma unroll
    for (int off = 32; off > 0; off >>= 1) vv += __shfl_xor(vv, off, 64);
    if (t == 0) out[b] = 1.0f / (1.0f + expf(-(vv + b3[0])));
  }
}

extern "C" void kernel_launch(void* const* d_in, const int* in_sizes, int n_in,
                              void* d_out, int out_size, void* d_ws, size_t ws_size,
                              hipStream_t stream)
{
  const int*   x_ids = (const int*)d_in[0];
  const int*   ei    = (const int*)d_in[1];
  const float* emb   = (const float*)d_in[3];
  const float* Wl[3]  = {(const float*)d_in[4],  (const float*)d_in[8],  (const float*)d_in[12]};
  const float* blv[3] = {(const float*)d_in[5],  (const float*)d_in[9],  (const float*)d_in[13]};
  const float* Wr[3]  = {(const float*)d_in[6],  (const float*)d_in[10], (const float*)d_in[14]};
  const float* pv[3]  = {(const float*)d_in[7],  (const float*)d_in[11], (const float*)d_in[15]};
  const float* W1 = (const float*)d_in[16]; const float* b1 = (const float*)d_in[17];
  const float* W2 = (const float*)d_in[18]; const float* b2 = (const float*)d_in[19];
  const float* W3 = (const float*)d_in[20]; const float* b3 = (const float*)d_in[21];

  char* ws = (char*)d_ws;
  size_t off = 0;
  auto alloc = [&](size_t bytes) -> void* {
    void* ptr = ws + off; off += (bytes + 255) & ~(size_t)255; return ptr;
  };
  u16*   xA    = (u16*)  alloc((size_t)NNODES * DF * 2);   // features / agg ping
  u16*   xB    = (u16*)  alloc((size_t)NNODES * DF * 2);   // features / agg pong
  float* score = (float*)alloc((size_t)NNODES * 4);
  float* keep  = (float*)alloc((size_t)NNODES * 4);
  float* fac   = (float*)alloc((size_t)NNODES * 4);
  float* degf  = (float*)alloc((size_t)NNODES * 4);
  int*   csr   = (int*)  alloc((size_t)NEDGE * 4);
  int*   roff  = (int*)  alloc((size_t)NNODES * 4);
  int*   rcnt  = (int*)  alloc((size_t)NNODES * 4);
  int*   perm  = (int*)  alloc((size_t)NNODES * 4);
  u16*   wF    = (u16*)  alloc((size_t)3 * 64 * 64 * 8 * 2);
  float* xlp   = (float*)alloc((size_t)3 * NB * 8 * 256 * 4);
  (void)in_sizes; (void)n_in; (void)out_size;
  if (off > ws_size) return;   // graceful fail instead of OOB fault

  wcvt_k<<<192, 64, 0, stream>>>(Wl[0], Wr[0], Wl[1], Wr[1], Wl[2], Wr[2], wF);
  build_csr_k<<<NB, 1024, 0, stream>>>(ei, csr, roff, rcnt, degf, keep, perm);
  gather_k<<<NNODES * 16 / 256, 256, 0, stream>>>(x_ids, emb, xA, fac);
  const int Ks[3] = {K1, K2, K3};
  u16* F = xA;   // current features (unscaled)
  u16* G = xB;   // agg -> xn (in-place)
  for (int l = 0; l < 3; ++l) {
    agg_k<<<1024, 1024, 0, stream>>>(F, fac, degf, csr, roff, rcnt, perm, G);
    gemm_k<<<1024, 512, 0, stream>>>(G, F, fac, wF + (size_t)l * 32768,
                                     blv[l], pv[l], score);
    rank_k<<<NB, 1024, 0, stream>>>(score, pv[l], ei, keep, fac, degf,
                                    Ks[l], l < 2 ? 1 : 0);
    readout_k<<<NB * 8, 256, 0, stream>>>(G, fac, keep,
                                          xlp + (size_t)l * NB * 8 * 256);
    u16* tmp = F; F = G; G = tmp;   // xn becomes next layer's features
  }
  mlp_k<<<NB, 256, 0, stream>>>(xlp, W1, b1, W2, b2, W3, b3, (float*)d_out);
}

// Round 4
// 766.062 us; speedup vs baseline: 1.0224x; 1.0224x over previous
//
#include <hip/hip_runtime.h>
#include <math.h>

#define NNODES 262144      // B*N
#define NEDGE  2097152     // NNODES*DEG
#define NB     256         // graphs
#define NPG    1024        // nodes per graph
#define EPG    8192        // edges per graph
#define DF     128         // feature dim

typedef unsigned short u16;
typedef unsigned int   u32;
typedef __attribute__((ext_vector_type(8))) short  short8;   // 8 x bf16 (4 VGPRs)
typedef __attribute__((ext_vector_type(4))) float  floatx4;  // MFMA accumulator

static constexpr int K1 = 820, K2 = 656, K3 = 525;

// ---- bf16 helpers (manual, RTNE) ----
__device__ inline float bflo(u32 u) { union { u32 i; float f; } c; c.i = u << 16;          return c.f; }
__device__ inline float bfhi(u32 u) { union { u32 i; float f; } c; c.i = u & 0xffff0000u;  return c.f; }
__device__ inline u32   f2bf(float f) {
  union { float f; u32 i; } c; c.f = f;
  const u32 r = c.i + 0x7fffu + ((c.i >> 16) & 1u);
  return r >> 16;
}
__device__ inline void acc8(float* b, uint4 v) {
  b[0] += bflo(v.x); b[1] += bfhi(v.x);
  b[2] += bflo(v.y); b[3] += bfhi(v.y);
  b[4] += bflo(v.z); b[5] += bfhi(v.z);
  b[6] += bflo(v.w); b[7] += bfhi(v.w);
}
__device__ inline uint4 pack8(const float* s, float k) {
  uint4 o;
  o.x = f2bf(s[0] * k) | (f2bf(s[1] * k) << 16);
  o.y = f2bf(s[2] * k) | (f2bf(s[3] * k) << 16);
  o.z = f2bf(s[4] * k) | (f2bf(s[5] * k) << 16);
  o.w = f2bf(s[6] * k) | (f2bf(s[7] * k) << 16);
  return o;
}

// ---------------- CSR build (1024 thr): counting sort by dst + deg/keep init ----
__global__ __launch_bounds__(1024) void build_csr_k(
    const int* __restrict__ ei, int* __restrict__ csr_src,
    int* __restrict__ row_off, int* __restrict__ row_cnt,
    float* __restrict__ degf, float* __restrict__ keep,
    int* __restrict__ perm)
{
  __shared__ int cnt[NPG];
  __shared__ int roff[NPG];
  __shared__ int wsum[NPG];
  __shared__ int hist[64];
  __shared__ int hoff[64];
  const int b = blockIdx.x, t = threadIdx.x;   // t in 0..1023
  const int* src = ei;
  const int* dst = ei + NEDGE;
  const int e0 = b * EPG;
  cnt[t] = 0;
  __syncthreads();
  for (int e = t; e < EPG; e += 1024) atomicAdd(&cnt[dst[e0 + e] & (NPG - 1)], 1);
  __syncthreads();
  const int v = cnt[t];
  wsum[t] = v;
  __syncthreads();
  for (int off = 1; off < NPG; off <<= 1) {
    const int u = (t >= off) ? wsum[t - off] : 0;
    __syncthreads();
    wsum[t] += u;
    __syncthreads();
  }
  const int base = wsum[t] - v;    // exclusive prefix
  roff[t] = base;
  const int n = b * NPG + t;
  row_off[n] = base;
  row_cnt[n] = v;
  degf[n]    = (float)v;           // layer-1 deg = full in-degree
  keep[n]    = 1.0f;
  if (t < 64) hist[t] = 0;
  __syncthreads();
  for (int e = t; e < EPG; e += 1024) {
    const int dl = dst[e0 + e] & (NPG - 1);
    const int pos = atomicAdd(&roff[dl], 1);
    csr_src[e0 + pos] = src[e0 + e];   // store GLOBAL src node id
  }
  // ---- degree-sorted permutation (counting sort over clamped degree) ----
  const int bkt = (v < 63) ? v : 63;
  atomicAdd(&hist[bkt], 1);
  __syncthreads();
  if (t == 0) {
    int s = 0;
#pragma unroll 1
    for (int i = 0; i < 64; ++i) { const int h = hist[i]; hoff[i] = s; s += h; }
  }
  __syncthreads();
  const int pp = atomicAdd(&hoff[bkt], 1);
  perm[b * NPG + pp] = t;
}

// ---------------- Embedding gather (f32 -> bf16, unscaled) + fac init -----------
__global__ __launch_bounds__(256) void gather_k(
    const int* __restrict__ x_ids, const float* __restrict__ emb,
    u16* __restrict__ x0, float* __restrict__ fac)
{
  const int gid = blockIdx.x * 256 + threadIdx.x;  // NNODES*16 threads
  const int n = gid >> 4, c = gid & 15;
  const int id = x_ids[n];
  const float4 v0 = *(const float4*)(emb + (size_t)id * DF + c * 8);
  const float4 v1 = *(const float4*)(emb + (size_t)id * DF + c * 8 + 4);
  uint4 pk;
  pk.x = f2bf(v0.x) | (f2bf(v0.y) << 16);
  pk.y = f2bf(v0.z) | (f2bf(v0.w) << 16);
  pk.z = f2bf(v1.x) | (f2bf(v1.y) << 16);
  pk.w = f2bf(v1.z) | (f2bf(v1.w) << 16);
  *(uint4*)(x0 + (size_t)n * DF + c * 8) = pk;
  if (c == 0) fac[n] = 1.0f;
}

// ---- Weight convert into SWIZZLED fragment order -------------------------------
// wF[l][f=ct*8+ks][lane][j] = wT[n=ct*16+(lane&15)][k=ks*32+(lane>>4)*8+j]
// where wT[n][k] = k<128 ? Wl[k][n] : Wr[k-128][n].  One wave per (l,f).
__global__ __launch_bounds__(64) void wcvt_k(
    const float* __restrict__ Wl1, const float* __restrict__ Wr1,
    const float* __restrict__ Wl2, const float* __restrict__ Wr2,
    const float* __restrict__ Wl3, const float* __restrict__ Wr3,
    u16* __restrict__ wF)
{
  const int f = blockIdx.x & 63, l = blockIdx.x >> 6;
  const int lane = threadIdx.x;
  const int ct = f >> 3, ks = f & 7;
  const int n = ct * 16 + (lane & 15);
  const int k0 = ks * 32 + (lane >> 4) * 8;
  const float* Wl = (l == 0) ? Wl1 : (l == 1) ? Wl2 : Wl3;
  const float* Wr = (l == 0) ? Wr1 : (l == 1) ? Wr2 : Wr3;
  u16 o[8];
#pragma unroll
  for (int j = 0; j < 8; ++j) {
    const int k = k0 + j;
    const float v = (k < 128) ? Wl[k * 128 + n] : Wr[(k - 128) * 128 + n];
    o[j] = (u16)f2bf(v);
  }
  uint4 pk;
  pk.x = (u32)o[0] | ((u32)o[1] << 16);
  pk.y = (u32)o[2] | ((u32)o[3] << 16);
  pk.z = (u32)o[4] | ((u32)o[5] << 16);
  pk.w = (u32)o[6] | ((u32)o[7] << 16);
  *(uint4*)(wF + (((size_t)l * 64 + f) * 64 + lane) * 8) = pk;
}

// ---- Aggregation v4: LDS-staged gather, degree-sorted thread->node map ---------
__global__ __launch_bounds__(1024) void agg_k(
    const u16* __restrict__ xprev, const float* __restrict__ fac,
    const float* __restrict__ deg,
    const int* __restrict__ csr_src, const int* __restrict__ row_off,
    const int* __restrict__ row_cnt, const int* __restrict__ perm,
    u16* __restrict__ aggb)
{
  __shared__ u32 xl[16384];          // 64 KB: 1024 rows x 16 dwords (32 bf16)
  const int t = threadIdx.x;
  const int bi = blockIdx.x;         // 1024 = 256 graphs x 4 quarters
  const int g  = (bi & 7) + 8 * (bi >> 5);     // XCD swizzle
  const int qt = (bi >> 3) & 3;
  const int n  = g * NPG + t;
  // ---- stage (scaled, swizzled) ----
  {
    const float fr = fac[n];
    const uint4* src = (const uint4*)(xprev + (size_t)n * DF + qt * 32);
    u32* dst = xl + t * 16;
    const int sw = (t & 3) << 2;
#pragma unroll
    for (int j = 0; j < 4; ++j) {
      const uint4 v = src[j];
      uint4 o;
      o.x = f2bf(bflo(v.x) * fr) | (f2bf(bfhi(v.x) * fr) << 16);
      o.y = f2bf(bflo(v.y) * fr) | (f2bf(bfhi(v.y) * fr) << 16);
      o.z = f2bf(bflo(v.z) * fr) | (f2bf(bfhi(v.z) * fr) << 16);
      o.w = f2bf(bflo(v.w) * fr) | (f2bf(bfhi(v.w) * fr) << 16);
      *(uint4*)(dst + ((j << 2) ^ sw)) = o;
    }
  }
  const int m  = perm[n];            // node this thread aggregates
  const int nm = g * NPG + m;
  __syncthreads();
  // ---- gather-sum from LDS ----
  const int cnt = row_cnt[nm];
  const int* ep = csr_src + g * EPG + row_off[nm];
  float b[32];
#pragma unroll
  for (int j = 0; j < 32; ++j) b[j] = 0.0f;
  int e = 0;
  for (; e + 2 <= cnt; e += 2) {
    const int s0 = ep[e] & (NPG - 1), s1 = ep[e + 1] & (NPG - 1);
    const u32* r0 = xl + s0 * 16; const int w0 = (s0 & 3) << 2;
    const u32* r1 = xl + s1 * 16; const int w1 = (s1 & 3) << 2;
    const uint4 A0 = *(const uint4*)(r0 + (0  ^ w0));
    const uint4 A1 = *(const uint4*)(r0 + (4  ^ w0));
    const uint4 A2 = *(const uint4*)(r0 + (8  ^ w0));
    const uint4 A3 = *(const uint4*)(r0 + (12 ^ w0));
    const uint4 B0 = *(const uint4*)(r1 + (0  ^ w1));
    const uint4 B1 = *(const uint4*)(r1 + (4  ^ w1));
    const uint4 B2 = *(const uint4*)(r1 + (8  ^ w1));
    const uint4 B3 = *(const uint4*)(r1 + (12 ^ w1));
    acc8(b + 0, A0); acc8(b + 8, A1); acc8(b + 16, A2); acc8(b + 24, A3);
    acc8(b + 0, B0); acc8(b + 8, B1); acc8(b + 16, B2); acc8(b + 24, B3);
  }
  if (e < cnt) {
    const int s0 = ep[e] & (NPG - 1);
    const u32* r0 = xl + s0 * 16; const int w0 = (s0 & 3) << 2;
    const uint4 A0 = *(const uint4*)(r0 + (0  ^ w0));
    const uint4 A1 = *(const uint4*)(r0 + (4  ^ w0));
    const uint4 A2 = *(const uint4*)(r0 + (8  ^ w0));
    const uint4 A3 = *(const uint4*)(r0 + (12 ^ w0));
    acc8(b + 0, A0); acc8(b + 8, A1); acc8(b + 16, A2); acc8(b + 24, A3);
  }
  const float inv = 1.0f / fmaxf(deg[nm], 1.0f);
  uint4* op = (uint4*)(aggb + (size_t)nm * DF + qt * 32);
  op[0] = pack8(b + 0,  inv);
  op[1] = pack8(b + 8,  inv);
  op[2] = pack8(b + 16, inv);
  op[3] = pack8(b + 24, inv);
}

// ---- MFMA GEMM v5: barrier-free, 3rd output buffer, 2-stage tile prefetch ------
// Writes xn to H (not in place) -> the ch-pair read/write race disappears, so
// there are ZERO per-tile barriers (no vmcnt(0) drains in the loop). Tile t+1's
// 9 loads are issued before tile t's MFMAs: one load batch always in flight per
// wave, hiding ~900cyc HBM/L3 latency even at ~2 waves/SIMD occupancy.
__global__ __launch_bounds__(512) void gemm_nb_k(
    const u16* __restrict__ G, const u16* __restrict__ F,
    const float* __restrict__ fac,
    const u16* __restrict__ wF, const float* __restrict__ bl,
    const float* __restrict__ p, u16* __restrict__ H,
    float* __restrict__ score)
{
  __shared__ float sc[256][2];
  const int t = threadIdx.x;
  const int bi = blockIdx.x;           // 1024 = 256 graphs x 4
  const int g   = (bi & 7) + 8 * (bi >> 5);
  const int tpg = (bi >> 3) & 3;
  const int n0  = g * NPG + tpg * 256;
  const int wv = t >> 6, lane = t & 63;
  const int rg = wv >> 1, ch = wv & 1;
  const int lr = lane & 15, quad = lane >> 4;

  // weights as MFMA *A* operand, held in registers for the whole kernel
  short8 bf[4][8];
#pragma unroll
  for (int ct = 0; ct < 4; ++ct)
#pragma unroll
    for (int ks = 0; ks < 8; ++ks) {
      const int f = (ch * 4 + ct) * 8 + ks;
      bf[ct][ks] = *(const short8*)(wF + ((size_t)f * 64 + lane) * 8);
    }
  float4 bn4[4], pn4[4];
#pragma unroll
  for (int ct = 0; ct < 4; ++ct) {
    const int fb = ch * 64 + ct * 16 + quad * 4;
    bn4[ct] = *(const float4*)(bl + fb);
    pn4[ct] = *(const float4*)(p + fb);
  }

  const int rb0 = n0 + rg * 64 + lr;
  // ---- prologue: load tile 0; zero-init prefetch regs (no UB on any path) ----
  short8 agc[4], axc[4], agn[4], axn[4];
  float frc, frn = 0.0f;
#pragma unroll
  for (int ks = 0; ks < 4; ++ks) {
    agn[ks] = (short8)(short)0;
    axn[ks] = (short8)(short)0;
    agc[ks] = *(const short8*)(G + (size_t)rb0 * DF + ks * 32 + quad * 8);
    axc[ks] = *(const short8*)(F + (size_t)rb0 * DF + ks * 32 + quad * 8);
  }
  frc = fac[rb0];

#pragma unroll
  for (int tl = 0; tl < 4; ++tl) {
    const int row = rb0 + tl * 16;
    // ---- prefetch tile tl+1 (issued before any use of current batch) ----
    if (tl < 3) {
      const int rown = row + 16;
#pragma unroll
      for (int ks = 0; ks < 4; ++ks) {
        agn[ks] = *(const short8*)(G + (size_t)rown * DF + ks * 32 + quad * 8);
        axn[ks] = *(const short8*)(F + (size_t)rown * DF + ks * 32 + quad * 8);
      }
      frn = fac[rown];
    }
    // ---- compute current tile ----
    floatx4 aL[4], aR[4];
#pragma unroll
    for (int ct = 0; ct < 4; ++ct) {
      aL[ct] = (floatx4){0.f, 0.f, 0.f, 0.f};
      aR[ct] = (floatx4){0.f, 0.f, 0.f, 0.f};
    }
#pragma unroll
    for (int ks = 0; ks < 4; ++ks)
#pragma unroll
      for (int ct = 0; ct < 4; ++ct) {
        aL[ct] = __builtin_amdgcn_mfma_f32_16x16x32_bf16(bf[ct][ks],     agc[ks], aL[ct], 0, 0, 0);
        aR[ct] = __builtin_amdgcn_mfma_f32_16x16x32_bf16(bf[ct][ks + 4], axc[ks], aR[ct], 0, 0, 0);
      }
    float si = 0.0f;
#pragma unroll
    for (int ct = 0; ct < 4; ++ct) {
      float v0 = fmaxf(aL[ct][0] + frc * aR[ct][0] + bn4[ct].x, 0.0f);
      float v1 = fmaxf(aL[ct][1] + frc * aR[ct][1] + bn4[ct].y, 0.0f);
      float v2 = fmaxf(aL[ct][2] + frc * aR[ct][2] + bn4[ct].z, 0.0f);
      float v3 = fmaxf(aL[ct][3] + frc * aR[ct][3] + bn4[ct].w, 0.0f);
      si += v0 * pn4[ct].x + v1 * pn4[ct].y + v2 * pn4[ct].z + v3 * pn4[ct].w;
      uint2 st;
      st.x = f2bf(v0) | (f2bf(v1) << 16);
      st.y = f2bf(v2) | (f2bf(v3) << 16);
      *(uint2*)(H + (size_t)row * DF + ch * 64 + ct * 16 + quad * 4) = st;
    }
    si += __shfl_xor(si, 16, 64);
    si += __shfl_xor(si, 32, 64);
    if (lane < 16) sc[rg * 64 + tl * 16 + lr][ch] = si;
    // ---- rotate pipeline regs (SSA-renamed by full unroll) ----
#pragma unroll
    for (int ks = 0; ks < 4; ++ks) { agc[ks] = agn[ks]; axc[ks] = axn[ks]; }
    frc = frn;
  }
  __syncthreads();   // the only barrier: sc complete across ch pair
  if (t < 256) score[n0 + t] = sc[t][0] + sc[t][1];
}

// ---- MFMA GEMM v4 (fallback if workspace lacks a 3rd buffer): in-place ---------
__global__ __launch_bounds__(512) void gemm_k(
    u16* __restrict__ G, const u16* __restrict__ F,
    const float* __restrict__ fac,
    const u16* __restrict__ wF, const float* __restrict__ bl,
    const float* __restrict__ p, float* __restrict__ score)
{
  __shared__ float sc[256][2];
  const int t = threadIdx.x;
  const int bi = blockIdx.x;           // 1024 = 256 graphs x 4
  const int g   = (bi & 7) + 8 * (bi >> 5);
  const int tpg = (bi >> 3) & 3;
  const int n0  = g * NPG + tpg * 256;
  const int wv = t >> 6, lane = t & 63;
  const int rg = wv >> 1, ch = wv & 1;
  const int lr = lane & 15, quad = lane >> 4;

  short8 bf[4][8];
#pragma unroll
  for (int ct = 0; ct < 4; ++ct)
#pragma unroll
    for (int ks = 0; ks < 8; ++ks) {
      const int f = (ch * 4 + ct) * 8 + ks;
      bf[ct][ks] = *(const short8*)(wF + ((size_t)f * 64 + lane) * 8);
    }
  float4 bn4[4], pn4[4];
#pragma unroll
  for (int ct = 0; ct < 4; ++ct) {
    const int fb = ch * 64 + ct * 16 + quad * 4;
    bn4[ct] = *(const float4*)(bl + fb);
    pn4[ct] = *(const float4*)(p + fb);
  }

#pragma unroll 1
  for (int tl = 0; tl < 4; ++tl) {
    const int rbase = n0 + rg * 64 + tl * 16;
    const int row = rbase + lr;
    short8 ag[4], ax[4];
#pragma unroll
    for (int ks = 0; ks < 4; ++ks) {
      ag[ks] = *(const short8*)(G + (size_t)row * DF + ks * 32 + quad * 8);
      ax[ks] = *(const short8*)(F + (size_t)row * DF + ks * 32 + quad * 8);
    }
    const float fr = fac[row];
    floatx4 aL[4], aR[4];
#pragma unroll
    for (int ct = 0; ct < 4; ++ct) {
      aL[ct] = (floatx4){0.f, 0.f, 0.f, 0.f};
      aR[ct] = (floatx4){0.f, 0.f, 0.f, 0.f};
    }
#pragma unroll
    for (int ks = 0; ks < 4; ++ks)
#pragma unroll
      for (int ct = 0; ct < 4; ++ct) {
        aL[ct] = __builtin_amdgcn_mfma_f32_16x16x32_bf16(bf[ct][ks],     ag[ks], aL[ct], 0, 0, 0);
        aR[ct] = __builtin_amdgcn_mfma_f32_16x16x32_bf16(bf[ct][ks + 4], ax[ks], aR[ct], 0, 0, 0);
      }
    float si = 0.0f;
    u32 pk[4][2];
#pragma unroll
    for (int ct = 0; ct < 4; ++ct) {
      float v0 = fmaxf(aL[ct][0] + fr * aR[ct][0] + bn4[ct].x, 0.0f);
      float v1 = fmaxf(aL[ct][1] + fr * aR[ct][1] + bn4[ct].y, 0.0f);
      float v2 = fmaxf(aL[ct][2] + fr * aR[ct][2] + bn4[ct].z, 0.0f);
      float v3 = fmaxf(aL[ct][3] + fr * aR[ct][3] + bn4[ct].w, 0.0f);
      si += v0 * pn4[ct].x + v1 * pn4[ct].y + v2 * pn4[ct].z + v3 * pn4[ct].w;
      pk[ct][0] = f2bf(v0) | (f2bf(v1) << 16);
      pk[ct][1] = f2bf(v2) | (f2bf(v3) << 16);
    }
    si += __shfl_xor(si, 16, 64);
    si += __shfl_xor(si, 32, 64);
    if (lane < 16) sc[rg * 64 + tl * 16 + lr][ch] = si;
    __syncthreads();
#pragma unroll
    for (int ct = 0; ct < 4; ++ct) {
      uint2 st; st.x = pk[ct][0]; st.y = pk[ct][1];
      *(uint2*)(G + (size_t)row * DF + ch * 64 + ct * 16 + quad * 4) = st;
    }
  }
  if (t < 256) score[n0 + t] = sc[t][0] + sc[t][1];
}

// ---- Per-graph top-k rank (exact argsort semantics) + edge-parallel next-deg ---
__global__ __launch_bounds__(1024) void rank_k(
    const float* __restrict__ score, const float* __restrict__ p,
    const int* __restrict__ ei,
    float* __restrict__ keep, float* __restrict__ fac,
    float* __restrict__ degN, int K, int next)
{
  __shared__ float s_lds[NPG];
  __shared__ float kfl[NPG];
  __shared__ float deg_l[NPG];
  const int b = blockIdx.x, t = threadIdx.x;
  float ssq = 0.0f;
  for (int d = 0; d < DF; ++d) ssq += p[d] * p[d];
  const float inv_pn = 1.0f / sqrtf(ssq);
  const float NEG = -__builtin_huge_valf();
  {
    const int n = b * NPG + t;
    s_lds[t] = (keep[n] > 0.5f) ? score[n] : NEG;
    deg_l[t] = 0.0f;
  }
  __syncthreads();
  const float si = s_lds[t];
  int rk = 0;
  for (int j = 0; j < NPG; ++j) {
    const float sj = s_lds[j];
    rk += (sj > si) || ((sj == si) && (j < t));
  }
  const bool kp = rk < K;          // implies previously-active (inactive = -inf)
  const int n = b * NPG + t;
  keep[n] = kp ? 1.0f : 0.0f;
  kfl[t]  = kp ? 1.0f : 0.0f;
  fac[n]  = kp ? tanhf(si * inv_pn) : 0.0f;
  __syncthreads();
  if (next) {
    const int e0 = b * EPG;
    for (int e = t; e < EPG; e += 1024) {
      const int sl = ei[e0 + e] & (NPG - 1);
      const int dl = ei[NEDGE + e0 + e] & (NPG - 1);
      atomicAdd(&deg_l[dl], kfl[sl]);
    }
    __syncthreads();
    degN[n] = deg_l[t];
  }
}

// ---- Parallel masked readout: 8 blocks/graph (reads unscaled xn, applies fac) --
__global__ __launch_bounds__(256) void readout_k(
    const u16* __restrict__ xn, const float* __restrict__ fac,
    const float* __restrict__ keep, float* __restrict__ xlp)
{
  __shared__ float mxA[256], mxB[256], smA[256], smB[256];
  const int blk = blockIdx.x, b = blk >> 3, pr = blk & 7, t = threadIdx.x;
  const int d = t & 63, rq = t >> 6;
  const float NEG = -__builtin_huge_valf();
  float mx0 = NEG, mx1 = NEG, sm0 = 0.0f, sm1 = 0.0f;
  for (int j = 0; j < 32; ++j) {
    const int n = b * NPG + pr * 128 + rq + j * 4;
    const float kf = keep[n];
    const float f  = fac[n];
    const u32 u = *(const u32*)(xn + (size_t)n * DF + d * 2);
    const float v0 = bflo(u) * f, v1 = bfhi(u) * f;
    if (kf > 0.5f) {
      mx0 = fmaxf(mx0, v0); mx1 = fmaxf(mx1, v1);
      sm0 += v0; sm1 += v1;
    }
  }
  mxA[t] = mx0; mxB[t] = mx1; smA[t] = sm0; smB[t] = sm1;
  __syncthreads();
  if (t < 64) {
    float m0 = mxA[t], m1 = mxB[t], s0 = smA[t], s1 = smB[t];
#pragma unroll
    for (int qq = 1; qq < 4; ++qq) {
      m0 = fmaxf(m0, mxA[qq * 64 + t]); m1 = fmaxf(m1, mxB[qq * 64 + t]);
      s0 += smA[qq * 64 + t];           s1 += smB[qq * 64 + t];
    }
    float* o = xlp + (size_t)blk * 256;
    o[2 * t]           = m0;
    o[2 * t + 1]       = m1;
    o[128 + 2 * t]     = s0;
    o[128 + 2 * t + 1] = s1;
  }
}

// ---------------- Final MLP head, one block per graph ----------------
__global__ __launch_bounds__(256) void mlp_k(
    const float* __restrict__ xlp,
    const float* __restrict__ W1, const float* __restrict__ b1,
    const float* __restrict__ W2, const float* __restrict__ b2,
    const float* __restrict__ W3, const float* __restrict__ b3,
    float* __restrict__ out)
{
  __shared__ float h0[256];
  __shared__ float h1[128];
  __shared__ float h2[64];
  const int b = blockIdx.x, t = threadIdx.x;
  const float invK[3] = {1.0f / (float)K1, 1.0f / (float)K2, 1.0f / (float)K3};
  float v = 0.0f;
#pragma unroll
  for (int l = 0; l < 3; ++l) {
    const float* base = xlp + ((size_t)l * NB * 8 + (size_t)b * 8) * 256;
    if (t < 128) {
      float m = base[t];
#pragma unroll
      for (int pr = 1; pr < 8; ++pr) m = fmaxf(m, base[pr * 256 + t]);
      v += m;
    } else {
      float s = 0.0f;
#pragma unroll
      for (int pr = 0; pr < 8; ++pr) s += base[pr * 256 + t];
      v += s * invK[l];
    }
  }
  h0[t] = v;
  __syncthreads();
  if (t < 128) {
    float a = b1[t];
    for (int k = 0; k < 256; ++k) a += h0[k] * W1[k * 128 + t];
    h1[t] = fmaxf(a, 0.0f);
  }
  __syncthreads();
  if (t < 64) {
    float a = b2[t];
    for (int k = 0; k < 128; ++k) a += h1[k] * W2[k * 64 + t];
    h2[t] = fmaxf(a, 0.0f);
  }
  __syncthreads();
  if (t < 64) {
    float vv = h2[t] * W3[t];
#pragma unroll
    for (int off = 32; off > 0; off >>= 1) vv += __shfl_xor(vv, off, 64);
    if (t == 0) out[b] = 1.0f / (1.0f + expf(-(vv + b3[0])));
  }
}

extern "C" void kernel_launch(void* const* d_in, const int* in_sizes, int n_in,
                              void* d_out, int out_size, void* d_ws, size_t ws_size,
                              hipStream_t stream)
{
  const int*   x_ids = (const int*)d_in[0];
  const int*   ei    = (const int*)d_in[1];
  const float* emb   = (const float*)d_in[3];
  const float* Wl[3]  = {(const float*)d_in[4],  (const float*)d_in[8],  (const float*)d_in[12]};
  const float* blv[3] = {(const float*)d_in[5],  (const float*)d_in[9],  (const float*)d_in[13]};
  const float* Wr[3]  = {(const float*)d_in[6],  (const float*)d_in[10], (const float*)d_in[14]};
  const float* pv[3]  = {(const float*)d_in[7],  (const float*)d_in[11], (const float*)d_in[15]};
  const float* W1 = (const float*)d_in[16]; const float* b1 = (const float*)d_in[17];
  const float* W2 = (const float*)d_in[18]; const float* b2 = (const float*)d_in[19];
  const float* W3 = (const float*)d_in[20]; const float* b3 = (const float*)d_in[21];

  char* ws = (char*)d_ws;
  size_t off = 0;
  auto alloc = [&](size_t bytes) -> void* {
    void* ptr = ws + off; off += (bytes + 255) & ~(size_t)255; return ptr;
  };
  u16*   xA    = (u16*)  alloc((size_t)NNODES * DF * 2);   // feature ping
  u16*   xB    = (u16*)  alloc((size_t)NNODES * DF * 2);   // agg buffer
  float* score = (float*)alloc((size_t)NNODES * 4);
  float* keep  = (float*)alloc((size_t)NNODES * 4);
  float* fac   = (float*)alloc((size_t)NNODES * 4);
  float* degf  = (float*)alloc((size_t)NNODES * 4);
  int*   csr   = (int*)  alloc((size_t)NEDGE * 4);
  int*   roff  = (int*)  alloc((size_t)NNODES * 4);
  int*   rcnt  = (int*)  alloc((size_t)NNODES * 4);
  int*   perm  = (int*)  alloc((size_t)NNODES * 4);
  u16*   wF    = (u16*)  alloc((size_t)3 * 64 * 64 * 8 * 2);
  float* xlp   = (float*)alloc((size_t)3 * NB * 8 * 256 * 4);
  const size_t off_base = off;
  u16*   xC    = (u16*)  alloc((size_t)NNODES * DF * 2);   // feature pong (v5 path)
  const bool use3 = (off <= ws_size);
  (void)in_sizes; (void)n_in; (void)out_size;
  if (off_base > ws_size) return;   // graceful fail instead of OOB fault

  wcvt_k<<<192, 64, 0, stream>>>(Wl[0], Wr[0], Wl[1], Wr[1], Wl[2], Wr[2], wF);
  build_csr_k<<<NB, 1024, 0, stream>>>(ei, csr, roff, rcnt, degf, keep, perm);
  gather_k<<<NNODES * 16 / 256, 256, 0, stream>>>(x_ids, emb, xA, fac);
  const int Ks[3] = {K1, K2, K3};
  if (use3) {
    // 3-buffer rotation: F/H ping-pong xA/xC, agg always in xB, no gemm barrier
    u16* F = xA;
    u16* H = xC;
    for (int l = 0; l < 3; ++l) {
      agg_k<<<1024, 1024, 0, stream>>>(F, fac, degf, csr, roff, rcnt, perm, xB);
      gemm_nb_k<<<1024, 512, 0, stream>>>(xB, F, fac, wF + (size_t)l * 32768,
                                          blv[l], pv[l], H, score);
      rank_k<<<NB, 1024, 0, stream>>>(score, pv[l], ei, keep, fac, degf,
                                      Ks[l], l < 2 ? 1 : 0);
      readout_k<<<NB * 8, 256, 0, stream>>>(H, fac, keep,
                                            xlp + (size_t)l * NB * 8 * 256);
      u16* tmp = F; F = H; H = tmp;
    }
  } else {
    u16* F = xA;
    u16* G = xB;
    for (int l = 0; l < 3; ++l) {
      agg_k<<<1024, 1024, 0, stream>>>(F, fac, degf, csr, roff, rcnt, perm, G);
      gemm_k<<<1024, 512, 0, stream>>>(G, F, fac, wF + (size_t)l * 32768,
                                       blv[l], pv[l], score);
      rank_k<<<NB, 1024, 0, stream>>>(score, pv[l], ei, keep, fac, degf,
                                      Ks[l], l < 2 ? 1 : 0);
      readout_k<<<NB * 8, 256, 0, stream>>>(G, fac, keep,
                                            xlp + (size_t)l * NB * 8 * 256);
      u16* tmp = F; F = G; G = tmp;
    }
  }
  mlp_k<<<NB, 256, 0, stream>>>(xlp, W1, b1, W2, b2, W3, b3, (float*)d_out);
}

// Round 5
// 743.316 us; speedup vs baseline: 1.0537x; 1.0306x over previous
//
#include <hip/hip_runtime.h>
#include <math.h>

#define NNODES 262144      // B*N
#define NEDGE  2097152     // NNODES*DEG
#define NB     256         // graphs
#define NPG    1024        // nodes per graph
#define EPG    8192        // edges per graph
#define DF     128         // feature dim

typedef unsigned short u16;
typedef unsigned int   u32;
typedef __attribute__((ext_vector_type(8))) short  short8;   // 8 x bf16 (4 VGPRs)
typedef __attribute__((ext_vector_type(4))) float  floatx4;  // MFMA accumulator
typedef __attribute__((ext_vector_type(2))) float  floatx2;  // v_pk_add_f32 target

static constexpr int K1 = 820, K2 = 656, K3 = 525;

// ---- bf16 helpers (manual, RTNE) ----
__device__ inline float bflo(u32 u) { union { u32 i; float f; } c; c.i = u << 16;          return c.f; }
__device__ inline float bfhi(u32 u) { union { u32 i; float f; } c; c.i = u & 0xffff0000u;  return c.f; }
__device__ inline u32   f2bf(float f) {
  union { float f; u32 i; } c; c.f = f;
  const u32 r = c.i + 0x7fffu + ((c.i >> 16) & 1u);
  return r >> 16;
}
__device__ inline floatx2 up2(u32 u) {
  floatx2 r; r.x = bflo(u); r.y = bfhi(u); return r;
}
// 4 dwords (8 bf16) -> 4 packed-f32 accumulators
__device__ inline void acc8(floatx2* b, uint4 v) {
  b[0] += up2(v.x); b[1] += up2(v.y); b[2] += up2(v.z); b[3] += up2(v.w);
}
__device__ inline uint4 pack8(const floatx2* s, float k) {
  uint4 o;
  o.x = f2bf(s[0].x * k) | (f2bf(s[0].y * k) << 16);
  o.y = f2bf(s[1].x * k) | (f2bf(s[1].y * k) << 16);
  o.z = f2bf(s[2].x * k) | (f2bf(s[2].y * k) << 16);
  o.w = f2bf(s[3].x * k) | (f2bf(s[3].y * k) << 16);
  return o;
}

// ---------------- CSR build (1024 thr): counting sort by dst + deg/keep init ----
__global__ __launch_bounds__(1024) void build_csr_k(
    const int* __restrict__ ei, int* __restrict__ csr_src,
    int* __restrict__ row_off, int* __restrict__ row_cnt,
    float* __restrict__ degf, float* __restrict__ keep,
    int* __restrict__ perm)
{
  __shared__ int cnt[NPG];
  __shared__ int roff[NPG];
  __shared__ int wsum[NPG];
  __shared__ int hist[64];
  __shared__ int hoff[64];
  const int b = blockIdx.x, t = threadIdx.x;   // t in 0..1023
  const int* src = ei;
  const int* dst = ei + NEDGE;
  const int e0 = b * EPG;
  cnt[t] = 0;
  __syncthreads();
  for (int e = t; e < EPG; e += 1024) atomicAdd(&cnt[dst[e0 + e] & (NPG - 1)], 1);
  __syncthreads();
  const int v = cnt[t];
  wsum[t] = v;
  __syncthreads();
  for (int off = 1; off < NPG; off <<= 1) {
    const int u = (t >= off) ? wsum[t - off] : 0;
    __syncthreads();
    wsum[t] += u;
    __syncthreads();
  }
  const int base = wsum[t] - v;    // exclusive prefix
  roff[t] = base;
  const int n = b * NPG + t;
  row_off[n] = base;
  row_cnt[n] = v;
  degf[n]    = (float)v;           // layer-1 deg = full in-degree
  keep[n]    = 1.0f;
  if (t < 64) hist[t] = 0;
  __syncthreads();
  for (int e = t; e < EPG; e += 1024) {
    const int dl = dst[e0 + e] & (NPG - 1);
    const int pos = atomicAdd(&roff[dl], 1);
    csr_src[e0 + pos] = src[e0 + e];   // store GLOBAL src node id
  }
  // ---- degree-sorted permutation (counting sort over clamped degree) ----
  const int bkt = (v < 63) ? v : 63;
  atomicAdd(&hist[bkt], 1);
  __syncthreads();
  if (t == 0) {
    int s = 0;
#pragma unroll 1
    for (int i = 0; i < 64; ++i) { const int h = hist[i]; hoff[i] = s; s += h; }
  }
  __syncthreads();
  const int pp = atomicAdd(&hoff[bkt], 1);
  perm[b * NPG + pp] = t;
}

// ---------------- Embedding gather (f32 -> bf16, unscaled) + fac init -----------
__global__ __launch_bounds__(256) void gather_k(
    const int* __restrict__ x_ids, const float* __restrict__ emb,
    u16* __restrict__ x0, float* __restrict__ fac)
{
  const int gid = blockIdx.x * 256 + threadIdx.x;  // NNODES*16 threads
  const int n = gid >> 4, c = gid & 15;
  const int id = x_ids[n];
  const float4 v0 = *(const float4*)(emb + (size_t)id * DF + c * 8);
  const float4 v1 = *(const float4*)(emb + (size_t)id * DF + c * 8 + 4);
  uint4 pk;
  pk.x = f2bf(v0.x) | (f2bf(v0.y) << 16);
  pk.y = f2bf(v0.z) | (f2bf(v0.w) << 16);
  pk.z = f2bf(v1.x) | (f2bf(v1.y) << 16);
  pk.w = f2bf(v1.z) | (f2bf(v1.w) << 16);
  *(uint4*)(x0 + (size_t)n * DF + c * 8) = pk;
  if (c == 0) fac[n] = 1.0f;
}

// ---- Weight convert into SWIZZLED fragment order -------------------------------
__global__ __launch_bounds__(64) void wcvt_k(
    const float* __restrict__ Wl1, const float* __restrict__ Wr1,
    const float* __restrict__ Wl2, const float* __restrict__ Wr2,
    const float* __restrict__ Wl3, const float* __restrict__ Wr3,
    u16* __restrict__ wF)
{
  const int f = blockIdx.x & 63, l = blockIdx.x >> 6;
  const int lane = threadIdx.x;
  const int ct = f >> 3, ks = f & 7;
  const int n = ct * 16 + (lane & 15);
  const int k0 = ks * 32 + (lane >> 4) * 8;
  const float* Wl = (l == 0) ? Wl1 : (l == 1) ? Wl2 : Wl3;
  const float* Wr = (l == 0) ? Wr1 : (l == 1) ? Wr2 : Wr3;
  u16 o[8];
#pragma unroll
  for (int j = 0; j < 8; ++j) {
    const int k = k0 + j;
    const float v = (k < 128) ? Wl[k * 128 + n] : Wr[(k - 128) * 128 + n];
    o[j] = (u16)f2bf(v);
  }
  uint4 pk;
  pk.x = (u32)o[0] | ((u32)o[1] << 16);
  pk.y = (u32)o[2] | ((u32)o[3] << 16);
  pk.z = (u32)o[4] | ((u32)o[5] << 16);
  pk.w = (u32)o[6] | ((u32)o[7] << 16);
  *(uint4*)(wF + (((size_t)l * 64 + f) * 64 + lane) * 8) = pk;
}

// ---- Aggregation v6: fixed 8-group XOR swizzle + pk_add accum + fused readout --
// Swizzle: group = 4*(row&1) + ((row>>1)&3) mod 8 -- bijective over all 8
// bank-groups (old (row&3) hit only 4 -> 16-way conflicts, the 18us/dispatch).
// If ro != null: after the gather, reduce the staged tile (= bf16(fac*x), i.e.
// the PREVIOUS layer's post-topk features) into per-graph masked max/sum --
// replaces a standalone 64MB-reading readout_k dispatch.
__global__ __launch_bounds__(1024) void agg_k(
    const u16* __restrict__ xprev, const float* __restrict__ fac,
    const float* __restrict__ keep, const float* __restrict__ deg,
    const int* __restrict__ csr_src, const int* __restrict__ row_off,
    const int* __restrict__ row_cnt, const int* __restrict__ perm,
    u16* __restrict__ aggb, float* __restrict__ ro)
{
  __shared__ u32 xl[16384];          // 64 KB: 1024 rows x 16 dwords (32 bf16)
  __shared__ float keepL[NPG];       // 4 KB
  __shared__ float4 scr[256];        // 4 KB readout partials
  const int t = threadIdx.x;
  const int bi = blockIdx.x;         // 1024 = 256 graphs x 4 quarters
  const int g  = (bi & 7) + 8 * (bi >> 5);     // XCD swizzle
  const int qt = (bi >> 3) & 3;
  const int n  = g * NPG + t;
  // ---- stage (scaled, swizzled) ----
  {
    const float fr = fac[n];
    const uint4* src = (const uint4*)(xprev + (size_t)n * DF + qt * 32);
    u32* dst = xl + t * 16;
    const int sw = ((t >> 1) & 3) << 2;
#pragma unroll
    for (int j = 0; j < 4; ++j) {
      const uint4 v = src[j];
      uint4 o;
      o.x = f2bf(bflo(v.x) * fr) | (f2bf(bfhi(v.x) * fr) << 16);
      o.y = f2bf(bflo(v.y) * fr) | (f2bf(bfhi(v.y) * fr) << 16);
      o.z = f2bf(bflo(v.z) * fr) | (f2bf(bfhi(v.z) * fr) << 16);
      o.w = f2bf(bflo(v.w) * fr) | (f2bf(bfhi(v.w) * fr) << 16);
      *(uint4*)(dst + ((j << 2) ^ sw)) = o;
    }
    if (ro) keepL[t] = keep[n];
  }
  const int m  = perm[n];            // node this thread aggregates
  const int nm = g * NPG + m;
  __syncthreads();
  // ---- gather-sum from LDS ----
  const int cnt = row_cnt[nm];
  const int* ep = csr_src + g * EPG + row_off[nm];
  floatx2 b[16];
#pragma unroll
  for (int j = 0; j < 16; ++j) b[j] = (floatx2){0.0f, 0.0f};
  int e = 0;
  for (; e + 2 <= cnt; e += 2) {
    const int s0 = ep[e] & (NPG - 1), s1 = ep[e + 1] & (NPG - 1);
    const u32* r0 = xl + s0 * 16; const int w0 = ((s0 >> 1) & 3) << 2;
    const u32* r1 = xl + s1 * 16; const int w1 = ((s1 >> 1) & 3) << 2;
    const uint4 A0 = *(const uint4*)(r0 + (0  ^ w0));
    const uint4 A1 = *(const uint4*)(r0 + (4  ^ w0));
    const uint4 A2 = *(const uint4*)(r0 + (8  ^ w0));
    const uint4 A3 = *(const uint4*)(r0 + (12 ^ w0));
    const uint4 B0 = *(const uint4*)(r1 + (0  ^ w1));
    const uint4 B1 = *(const uint4*)(r1 + (4  ^ w1));
    const uint4 B2 = *(const uint4*)(r1 + (8  ^ w1));
    const uint4 B3 = *(const uint4*)(r1 + (12 ^ w1));
    acc8(b + 0, A0); acc8(b + 4, A1); acc8(b + 8, A2); acc8(b + 12, A3);
    acc8(b + 0, B0); acc8(b + 4, B1); acc8(b + 8, B2); acc8(b + 12, B3);
  }
  if (e < cnt) {
    const int s0 = ep[e] & (NPG - 1);
    const u32* r0 = xl + s0 * 16; const int w0 = ((s0 >> 1) & 3) << 2;
    const uint4 A0 = *(const uint4*)(r0 + (0  ^ w0));
    const uint4 A1 = *(const uint4*)(r0 + (4  ^ w0));
    const uint4 A2 = *(const uint4*)(r0 + (8  ^ w0));
    const uint4 A3 = *(const uint4*)(r0 + (12 ^ w0));
    acc8(b + 0, A0); acc8(b + 4, A1); acc8(b + 8, A2); acc8(b + 12, A3);
  }
  const float inv = 1.0f / fmaxf(deg[nm], 1.0f);
  uint4* op = (uint4*)(aggb + (size_t)nm * DF + qt * 32);
  op[0] = pack8(b + 0,  inv);
  op[1] = pack8(b + 4,  inv);
  op[2] = pack8(b + 8,  inv);
  op[3] = pack8(b + 12, inv);
  // ---- fused readout of the PREVIOUS layer (staged tile = fac*x, masked) ----
  if (ro) {
    const int dw = t & 15, ck = t >> 4;          // dword col, 16-row chunk
    const float NEG = -__builtin_huge_valf();
    float mx0 = NEG, mx1 = NEG, sm0 = 0.0f, sm1 = 0.0f;
#pragma unroll
    for (int i = 0; i < 16; ++i) {
      const int r = ck * 16 + ((i + ck) & 15);   // stagger: 2-way banks, free
      const u32 u = xl[r * 16 + (dw ^ (((r >> 1) & 3) << 2))];
      if (keepL[r] > 0.5f) {
        const float lo = bflo(u), hi = bfhi(u);
        mx0 = fmaxf(mx0, lo); mx1 = fmaxf(mx1, hi);
        sm0 += lo; sm1 += hi;
      }
    }
    mx0 = fmaxf(mx0, __shfl_xor(mx0, 16, 64));
    mx1 = fmaxf(mx1, __shfl_xor(mx1, 16, 64));
    sm0 += __shfl_xor(sm0, 16, 64);
    sm1 += __shfl_xor(sm1, 16, 64);
    mx0 = fmaxf(mx0, __shfl_xor(mx0, 32, 64));
    mx1 = fmaxf(mx1, __shfl_xor(mx1, 32, 64));
    sm0 += __shfl_xor(sm0, 32, 64);
    sm1 += __shfl_xor(sm1, 32, 64);
    const int lane = t & 63, wv = t >> 6;
    if (lane < 16) scr[wv * 16 + dw] = make_float4(mx0, mx1, sm0, sm1);
    __syncthreads();
    if (t < 16) {
      float4 a = scr[t];
#pragma unroll 1
      for (int w = 1; w < 16; ++w) {
        const float4 c = scr[w * 16 + t];
        a.x = fmaxf(a.x, c.x); a.y = fmaxf(a.y, c.y);
        a.z += c.z; a.w += c.w;
      }
      float* o = ro + (size_t)g * 256;
      o[qt * 32 + 2 * t]           = a.x;
      o[qt * 32 + 2 * t + 1]       = a.y;
      o[128 + qt * 32 + 2 * t]     = a.z;
      o[128 + qt * 32 + 2 * t + 1] = a.w;
    }
  }
}

// ---- MFMA GEMM v5: barrier-free, 3rd output buffer, 2-stage tile prefetch ------
__global__ __launch_bounds__(512) void gemm_nb_k(
    const u16* __restrict__ G, const u16* __restrict__ F,
    const float* __restrict__ fac,
    const u16* __restrict__ wF, const float* __restrict__ bl,
    const float* __restrict__ p, u16* __restrict__ H,
    float* __restrict__ score)
{
  __shared__ float sc[256][2];
  const int t = threadIdx.x;
  const int bi = blockIdx.x;           // 1024 = 256 graphs x 4
  const int g   = (bi & 7) + 8 * (bi >> 5);
  const int tpg = (bi >> 3) & 3;
  const int n0  = g * NPG + tpg * 256;
  const int wv = t >> 6, lane = t & 63;
  const int rg = wv >> 1, ch = wv & 1;
  const int lr = lane & 15, quad = lane >> 4;

  short8 bf[4][8];
#pragma unroll
  for (int ct = 0; ct < 4; ++ct)
#pragma unroll
    for (int ks = 0; ks < 8; ++ks) {
      const int f = (ch * 4 + ct) * 8 + ks;
      bf[ct][ks] = *(const short8*)(wF + ((size_t)f * 64 + lane) * 8);
    }
  float4 bn4[4], pn4[4];
#pragma unroll
  for (int ct = 0; ct < 4; ++ct) {
    const int fb = ch * 64 + ct * 16 + quad * 4;
    bn4[ct] = *(const float4*)(bl + fb);
    pn4[ct] = *(const float4*)(p + fb);
  }

  const int rb0 = n0 + rg * 64 + lr;
  short8 agc[4], axc[4], agn[4], axn[4];
  float frc, frn = 0.0f;
#pragma unroll
  for (int ks = 0; ks < 4; ++ks) {
    agn[ks] = (short8)(short)0;
    axn[ks] = (short8)(short)0;
    agc[ks] = *(const short8*)(G + (size_t)rb0 * DF + ks * 32 + quad * 8);
    axc[ks] = *(const short8*)(F + (size_t)rb0 * DF + ks * 32 + quad * 8);
  }
  frc = fac[rb0];

#pragma unroll
  for (int tl = 0; tl < 4; ++tl) {
    const int row = rb0 + tl * 16;
    if (tl < 3) {
      const int rown = row + 16;
#pragma unroll
      for (int ks = 0; ks < 4; ++ks) {
        agn[ks] = *(const short8*)(G + (size_t)rown * DF + ks * 32 + quad * 8);
        axn[ks] = *(const short8*)(F + (size_t)rown * DF + ks * 32 + quad * 8);
      }
      frn = fac[rown];
    }
    floatx4 aL[4], aR[4];
#pragma unroll
    for (int ct = 0; ct < 4; ++ct) {
      aL[ct] = (floatx4){0.f, 0.f, 0.f, 0.f};
      aR[ct] = (floatx4){0.f, 0.f, 0.f, 0.f};
    }
#pragma unroll
    for (int ks = 0; ks < 4; ++ks)
#pragma unroll
      for (int ct = 0; ct < 4; ++ct) {
        aL[ct] = __builtin_amdgcn_mfma_f32_16x16x32_bf16(bf[ct][ks],     agc[ks], aL[ct], 0, 0, 0);
        aR[ct] = __builtin_amdgcn_mfma_f32_16x16x32_bf16(bf[ct][ks + 4], axc[ks], aR[ct], 0, 0, 0);
      }
    float si = 0.0f;
#pragma unroll
    for (int ct = 0; ct < 4; ++ct) {
      float v0 = fmaxf(aL[ct][0] + frc * aR[ct][0] + bn4[ct].x, 0.0f);
      float v1 = fmaxf(aL[ct][1] + frc * aR[ct][1] + bn4[ct].y, 0.0f);
      float v2 = fmaxf(aL[ct][2] + frc * aR[ct][2] + bn4[ct].z, 0.0f);
      float v3 = fmaxf(aL[ct][3] + frc * aR[ct][3] + bn4[ct].w, 0.0f);
      si += v0 * pn4[ct].x + v1 * pn4[ct].y + v2 * pn4[ct].z + v3 * pn4[ct].w;
      uint2 st;
      st.x = f2bf(v0) | (f2bf(v1) << 16);
      st.y = f2bf(v2) | (f2bf(v3) << 16);
      *(uint2*)(H + (size_t)row * DF + ch * 64 + ct * 16 + quad * 4) = st;
    }
    si += __shfl_xor(si, 16, 64);
    si += __shfl_xor(si, 32, 64);
    if (lane < 16) sc[rg * 64 + tl * 16 + lr][ch] = si;
#pragma unroll
    for (int ks = 0; ks < 4; ++ks) { agc[ks] = agn[ks]; axc[ks] = axn[ks]; }
    frc = frn;
  }
  __syncthreads();   // the only barrier: sc complete across ch pair
  if (t < 256) score[n0 + t] = sc[t][0] + sc[t][1];
}

// ---- MFMA GEMM v4 (fallback if workspace lacks a 3rd buffer): in-place ---------
__global__ __launch_bounds__(512) void gemm_k(
    u16* __restrict__ G, const u16* __restrict__ F,
    const float* __restrict__ fac,
    const u16* __restrict__ wF, const float* __restrict__ bl,
    const float* __restrict__ p, float* __restrict__ score)
{
  __shared__ float sc[256][2];
  const int t = threadIdx.x;
  const int bi = blockIdx.x;
  const int g   = (bi & 7) + 8 * (bi >> 5);
  const int tpg = (bi >> 3) & 3;
  const int n0  = g * NPG + tpg * 256;
  const int wv = t >> 6, lane = t & 63;
  const int rg = wv >> 1, ch = wv & 1;
  const int lr = lane & 15, quad = lane >> 4;

  short8 bf[4][8];
#pragma unroll
  for (int ct = 0; ct < 4; ++ct)
#pragma unroll
    for (int ks = 0; ks < 8; ++ks) {
      const int f = (ch * 4 + ct) * 8 + ks;
      bf[ct][ks] = *(const short8*)(wF + ((size_t)f * 64 + lane) * 8);
    }
  float4 bn4[4], pn4[4];
#pragma unroll
  for (int ct = 0; ct < 4; ++ct) {
    const int fb = ch * 64 + ct * 16 + quad * 4;
    bn4[ct] = *(const float4*)(bl + fb);
    pn4[ct] = *(const float4*)(p + fb);
  }

#pragma unroll 1
  for (int tl = 0; tl < 4; ++tl) {
    const int rbase = n0 + rg * 64 + tl * 16;
    const int row = rbase + lr;
    short8 ag[4], ax[4];
#pragma unroll
    for (int ks = 0; ks < 4; ++ks) {
      ag[ks] = *(const short8*)(G + (size_t)row * DF + ks * 32 + quad * 8);
      ax[ks] = *(const short8*)(F + (size_t)row * DF + ks * 32 + quad * 8);
    }
    const float fr = fac[row];
    floatx4 aL[4], aR[4];
#pragma unroll
    for (int ct = 0; ct < 4; ++ct) {
      aL[ct] = (floatx4){0.f, 0.f, 0.f, 0.f};
      aR[ct] = (floatx4){0.f, 0.f, 0.f, 0.f};
    }
#pragma unroll
    for (int ks = 0; ks < 4; ++ks)
#pragma unroll
      for (int ct = 0; ct < 4; ++ct) {
        aL[ct] = __builtin_amdgcn_mfma_f32_16x16x32_bf16(bf[ct][ks],     ag[ks], aL[ct], 0, 0, 0);
        aR[ct] = __builtin_amdgcn_mfma_f32_16x16x32_bf16(bf[ct][ks + 4], ax[ks], aR[ct], 0, 0, 0);
      }
    float si = 0.0f;
    u32 pk[4][2];
#pragma unroll
    for (int ct = 0; ct < 4; ++ct) {
      float v0 = fmaxf(aL[ct][0] + fr * aR[ct][0] + bn4[ct].x, 0.0f);
      float v1 = fmaxf(aL[ct][1] + fr * aR[ct][1] + bn4[ct].y, 0.0f);
      float v2 = fmaxf(aL[ct][2] + fr * aR[ct][2] + bn4[ct].z, 0.0f);
      float v3 = fmaxf(aL[ct][3] + fr * aR[ct][3] + bn4[ct].w, 0.0f);
      si += v0 * pn4[ct].x + v1 * pn4[ct].y + v2 * pn4[ct].z + v3 * pn4[ct].w;
      pk[ct][0] = f2bf(v0) | (f2bf(v1) << 16);
      pk[ct][1] = f2bf(v2) | (f2bf(v3) << 16);
    }
    si += __shfl_xor(si, 16, 64);
    si += __shfl_xor(si, 32, 64);
    if (lane < 16) sc[rg * 64 + tl * 16 + lr][ch] = si;
    __syncthreads();
#pragma unroll
    for (int ct = 0; ct < 4; ++ct) {
      uint2 st; st.x = pk[ct][0]; st.y = pk[ct][1];
      *(uint2*)(G + (size_t)row * DF + ch * 64 + ct * 16 + quad * 4) = st;
    }
  }
  if (t < 256) score[n0 + t] = sc[t][0] + sc[t][1];
}

// ---- Per-graph top-k rank (exact argsort semantics) + edge-parallel next-deg ---
__global__ __launch_bounds__(1024) void rank_k(
    const float* __restrict__ score, const float* __restrict__ p,
    const int* __restrict__ ei,
    float* __restrict__ keep, float* __restrict__ fac,
    float* __restrict__ degN, int K, int next)
{
  __shared__ float s_lds[NPG];
  __shared__ float kfl[NPG];
  __shared__ float deg_l[NPG];
  const int b = blockIdx.x, t = threadIdx.x;
  float ssq = 0.0f;
  for (int d = 0; d < DF; ++d) ssq += p[d] * p[d];
  const float inv_pn = 1.0f / sqrtf(ssq);
  const float NEG = -__builtin_huge_valf();
  {
    const int n = b * NPG + t;
    s_lds[t] = (keep[n] > 0.5f) ? score[n] : NEG;
    deg_l[t] = 0.0f;
  }
  __syncthreads();
  const float si = s_lds[t];
  int rk = 0;
  for (int j = 0; j < NPG; ++j) {
    const float sj = s_lds[j];
    rk += (sj > si) || ((sj == si) && (j < t));
  }
  const bool kp = rk < K;
  const int n = b * NPG + t;
  keep[n] = kp ? 1.0f : 0.0f;
  kfl[t]  = kp ? 1.0f : 0.0f;
  fac[n]  = kp ? tanhf(si * inv_pn) : 0.0f;
  __syncthreads();
  if (next) {
    const int e0 = b * EPG;
    for (int e = t; e < EPG; e += 1024) {
      const int sl = ei[e0 + e] & (NPG - 1);
      const int dl = ei[NEDGE + e0 + e] & (NPG - 1);
      atomicAdd(&deg_l[dl], kfl[sl]);
    }
    __syncthreads();
    degN[n] = deg_l[t];
  }
}

// ---- Parallel masked readout (layer 3 only): 8 blocks/graph, partial format ----
__global__ __launch_bounds__(256) void readout_k(
    const u16* __restrict__ xn, const float* __restrict__ fac,
    const float* __restrict__ keep, float* __restrict__ xlp)
{
  __shared__ float mxA[256], mxB[256], smA[256], smB[256];
  const int blk = blockIdx.x, b = blk >> 3, pr = blk & 7, t = threadIdx.x;
  const int d = t & 63, rq = t >> 6;
  const float NEG = -__builtin_huge_valf();
  float mx0 = NEG, mx1 = NEG, sm0 = 0.0f, sm1 = 0.0f;
  for (int j = 0; j < 32; ++j) {
    const int n = b * NPG + pr * 128 + rq + j * 4;
    const float kf = keep[n];
    const float f  = fac[n];
    const u32 u = *(const u32*)(xn + (size_t)n * DF + d * 2);
    const float v0 = bflo(u) * f, v1 = bfhi(u) * f;
    if (kf > 0.5f) {
      mx0 = fmaxf(mx0, v0); mx1 = fmaxf(mx1, v1);
      sm0 += v0; sm1 += v1;
    }
  }
  mxA[t] = mx0; mxB[t] = mx1; smA[t] = sm0; smB[t] = sm1;
  __syncthreads();
  if (t < 64) {
    float m0 = mxA[t], m1 = mxB[t], s0 = smA[t], s1 = smB[t];
#pragma unroll
    for (int qq = 1; qq < 4; ++qq) {
      m0 = fmaxf(m0, mxA[qq * 64 + t]); m1 = fmaxf(m1, mxB[qq * 64 + t]);
      s0 += smA[qq * 64 + t];           s1 += smB[qq * 64 + t];
    }
    float* o = xlp + (size_t)blk * 256;
    o[2 * t]           = m0;
    o[2 * t + 1]       = m1;
    o[128 + 2 * t]     = s0;
    o[128 + 2 * t + 1] = s1;
  }
}

// ---------------- Final MLP head, one block per graph ----------------
// Layers 0,1 from compact xlpF [2][NB][256] (mx 0..127 | sm 128..255);
// layer 2 from the 8-partial xlp2 format.
__global__ __launch_bounds__(256) void mlp_k(
    const float* __restrict__ xlpF, const float* __restrict__ xlp2,
    const float* __restrict__ W1, const float* __restrict__ b1,
    const float* __restrict__ W2, const float* __restrict__ b2,
    const float* __restrict__ W3, const float* __restrict__ b3,
    float* __restrict__ out)
{
  __shared__ float h0[256];
  __shared__ float h1[128];
  __shared__ float h2[64];
  const int b = blockIdx.x, t = threadIdx.x;
  const float invK[3] = {1.0f / (float)K1, 1.0f / (float)K2, 1.0f / (float)K3};
  const float* f0 = xlpF + (size_t)b * 256;
  const float* f1 = xlpF + (size_t)(NB + b) * 256;
  float v;
  if (t < 128) v = f0[t] + f1[t];
  else         v = f0[t] * invK[0] + f1[t] * invK[1];
  {
    const float* base = xlp2 + (size_t)b * 8 * 256;
    if (t < 128) {
      float m = base[t];
#pragma unroll
      for (int pr = 1; pr < 8; ++pr) m = fmaxf(m, base[pr * 256 + t]);
      v += m;
    } else {
      float s = 0.0f;
#pragma unroll
      for (int pr = 0; pr < 8; ++pr) s += base[pr * 256 + t];
      v += s * invK[2];
    }
  }
  h0[t] = v;
  __syncthreads();
  if (t < 128) {
    float a = b1[t];
    for (int k = 0; k < 256; ++k) a += h0[k] * W1[k * 128 + t];
    h1[t] = fmaxf(a, 0.0f);
  }
  __syncthreads();
  if (t < 64) {
    float a = b2[t];
    for (int k = 0; k < 128; ++k) a += h1[k] * W2[k * 64 + t];
    h2[t] = fmaxf(a, 0.0f);
  }
  __syncthreads();
  if (t < 64) {
    float vv = h2[t] * W3[t];
#pragma unroll
    for (int off = 32; off > 0; off >>= 1) vv += __shfl_xor(vv, off, 64);
    if (t == 0) out[b] = 1.0f / (1.0f + expf(-(vv + b3[0])));
  }
}

extern "C" void kernel_launch(void* const* d_in, const int* in_sizes, int n_in,
                              void* d_out, int out_size, void* d_ws, size_t ws_size,
                              hipStream_t stream)
{
  const int*   x_ids = (const int*)d_in[0];
  const int*   ei    = (const int*)d_in[1];
  const float* emb   = (const float*)d_in[3];
  const float* Wl[3]  = {(const float*)d_in[4],  (const float*)d_in[8],  (const float*)d_in[12]};
  const float* blv[3] = {(const float*)d_in[5],  (const float*)d_in[9],  (const float*)d_in[13]};
  const float* Wr[3]  = {(const float*)d_in[6],  (const float*)d_in[10], (const float*)d_in[14]};
  const float* pv[3]  = {(const float*)d_in[7],  (const float*)d_in[11], (const float*)d_in[15]};
  const float* W1 = (const float*)d_in[16]; const float* b1 = (const float*)d_in[17];
  const float* W2 = (const float*)d_in[18]; const float* b2 = (const float*)d_in[19];
  const float* W3 = (const float*)d_in[20]; const float* b3 = (const float*)d_in[21];

  char* ws = (char*)d_ws;
  size_t off = 0;
  auto alloc = [&](size_t bytes) -> void* {
    void* ptr = ws + off; off += (bytes + 255) & ~(size_t)255; return ptr;
  };
  u16*   xA    = (u16*)  alloc((size_t)NNODES * DF * 2);   // feature ping
  u16*   xB    = (u16*)  alloc((size_t)NNODES * DF * 2);   // agg buffer
  float* score = (float*)alloc((size_t)NNODES * 4);
  float* keep  = (float*)alloc((size_t)NNODES * 4);
  float* fac   = (float*)alloc((size_t)NNODES * 4);
  float* degf  = (float*)alloc((size_t)NNODES * 4);
  int*   csr   = (int*)  alloc((size_t)NEDGE * 4);
  int*   roff  = (int*)  alloc((size_t)NNODES * 4);
  int*   rcnt  = (int*)  alloc((size_t)NNODES * 4);
  int*   perm  = (int*)  alloc((size_t)NNODES * 4);
  u16*   wF    = (u16*)  alloc((size_t)3 * 64 * 64 * 8 * 2);
  float* xlpF  = (float*)alloc((size_t)2 * NB * 256 * 4);   // fused readout l0,l1
  float* xlp2  = (float*)alloc((size_t)NB * 8 * 256 * 4);   // partial readout l2
  const size_t off_base = off;
  u16*   xC    = (u16*)  alloc((size_t)NNODES * DF * 2);   // feature pong (v5 path)
  const bool use3 = (off <= ws_size);
  (void)in_sizes; (void)n_in; (void)out_size;
  if (off_base > ws_size) return;   // graceful fail instead of OOB fault

  wcvt_k<<<192, 64, 0, stream>>>(Wl[0], Wr[0], Wl[1], Wr[1], Wl[2], Wr[2], wF);
  build_csr_k<<<NB, 1024, 0, stream>>>(ei, csr, roff, rcnt, degf, keep, perm);
  gather_k<<<NNODES * 16 / 256, 256, 0, stream>>>(x_ids, emb, xA, fac);
  const int Ks[3] = {K1, K2, K3};
  if (use3) {
    u16* F = xA;
    u16* H = xC;
    for (int l = 0; l < 3; ++l) {
      float* ro = (l == 0) ? nullptr : xlpF + (size_t)(l - 1) * NB * 256;
      agg_k<<<1024, 1024, 0, stream>>>(F, fac, keep, degf, csr, roff, rcnt, perm,
                                       xB, ro);
      gemm_nb_k<<<1024, 512, 0, stream>>>(xB, F, fac, wF + (size_t)l * 32768,
                                          blv[l], pv[l], H, score);
      rank_k<<<NB, 1024, 0, stream>>>(score, pv[l], ei, keep, fac, degf,
                                      Ks[l], l < 2 ? 1 : 0);
      u16* tmp = F; F = H; H = tmp;   // xn (in F now) is next layer's features
    }
    readout_k<<<NB * 8, 256, 0, stream>>>(F, fac, keep, xlp2);   // layer 2
  } else {
    u16* F = xA;
    u16* G = xB;
    for (int l = 0; l < 3; ++l) {
      float* ro = (l == 0) ? nullptr : xlpF + (size_t)(l - 1) * NB * 256;
      agg_k<<<1024, 1024, 0, stream>>>(F, fac, keep, degf, csr, roff, rcnt, perm,
                                       G, ro);
      gemm_k<<<1024, 512, 0, stream>>>(G, F, fac, wF + (size_t)l * 32768,
                                       blv[l], pv[l], score);
      rank_k<<<NB, 1024, 0, stream>>>(score, pv[l], ei, keep, fac, degf,
                                      Ks[l], l < 2 ? 1 : 0);
      u16* tmp = F; F = G; G = tmp;
    }
    readout_k<<<NB * 8, 256, 0, stream>>>(F, fac, keep, xlp2);   // layer 2
  }
  mlp_k<<<NB, 256, 0, stream>>>(xlpF, xlp2, W1, b1, W2, b2, W3, b3, (float*)d_out);
}

// Round 6
// 719.883 us; speedup vs baseline: 1.0880x; 1.0326x over previous
//
#include <hip/hip_runtime.h>
#include <math.h>

#define NNODES 262144      // B*N
#define NEDGE  2097152     // NNODES*DEG
#define NB     256         // graphs
#define NPG    1024        // nodes per graph
#define EPG    8192        // edges per graph
#define DF     128         // feature dim

typedef unsigned short u16;
typedef unsigned int   u32;
typedef __attribute__((ext_vector_type(8))) short  short8;   // 8 x bf16 (4 VGPRs)
typedef __attribute__((ext_vector_type(4))) float  floatx4;  // MFMA accumulator

static constexpr int K1 = 820, K2 = 656, K3 = 525;

// ---- bf16 helpers (manual, RTNE) ----
__device__ inline float bflo(u32 u) { union { u32 i; float f; } c; c.i = u << 16;          return c.f; }
__device__ inline float bfhi(u32 u) { union { u32 i; float f; } c; c.i = u & 0xffff0000u;  return c.f; }
__device__ inline u32   f2bf(float f) {
  union { float f; u32 i; } c; c.f = f;
  const u32 r = c.i + 0x7fffu + ((c.i >> 16) & 1u);
  return r >> 16;
}
// scalar accumulate: 2 unpack + 2 add per dword (NO floatx2 -- v_pk_add_f32
// forces reg-pairing v_movs that cost MORE than the adds saved; measured R5)
__device__ inline void acc8(float* b, uint4 v) {
  b[0] += bflo(v.x); b[1] += bfhi(v.x);
  b[2] += bflo(v.y); b[3] += bfhi(v.y);
  b[4] += bflo(v.z); b[5] += bfhi(v.z);
  b[6] += bflo(v.w); b[7] += bfhi(v.w);
}
__device__ inline uint4 pack8(const float* s, float k) {
  uint4 o;
  o.x = f2bf(s[0] * k) | (f2bf(s[1] * k) << 16);
  o.y = f2bf(s[2] * k) | (f2bf(s[3] * k) << 16);
  o.z = f2bf(s[4] * k) | (f2bf(s[5] * k) << 16);
  o.w = f2bf(s[6] * k) | (f2bf(s[7] * k) << 16);
  return o;
}

// ---------------- CSR build (1024 thr): counting sort by dst + deg/keep init ----
__global__ __launch_bounds__(1024) void build_csr_k(
    const int* __restrict__ ei, int* __restrict__ csr_src,
    int* __restrict__ row_off, int* __restrict__ row_cnt,
    float* __restrict__ degf, float* __restrict__ keep,
    int* __restrict__ perm)
{
  __shared__ int cnt[NPG];
  __shared__ int roff[NPG];
  __shared__ int wsum[NPG];
  __shared__ int hist[64];
  __shared__ int hoff[64];
  const int b = blockIdx.x, t = threadIdx.x;   // t in 0..1023
  const int* src = ei;
  const int* dst = ei + NEDGE;
  const int e0 = b * EPG;
  cnt[t] = 0;
  __syncthreads();
  for (int e = t; e < EPG; e += 1024) atomicAdd(&cnt[dst[e0 + e] & (NPG - 1)], 1);
  __syncthreads();
  const int v = cnt[t];
  wsum[t] = v;
  __syncthreads();
  for (int off = 1; off < NPG; off <<= 1) {
    const int u = (t >= off) ? wsum[t - off] : 0;
    __syncthreads();
    wsum[t] += u;
    __syncthreads();
  }
  const int base = wsum[t] - v;    // exclusive prefix
  roff[t] = base;
  const int n = b * NPG + t;
  row_off[n] = base;
  row_cnt[n] = v;
  degf[n]    = (float)v;           // layer-1 deg = full in-degree
  keep[n]    = 1.0f;
  if (t < 64) hist[t] = 0;
  __syncthreads();
  for (int e = t; e < EPG; e += 1024) {
    const int dl = dst[e0 + e] & (NPG - 1);
    const int pos = atomicAdd(&roff[dl], 1);
    csr_src[e0 + pos] = src[e0 + e];   // store GLOBAL src node id
  }
  // ---- degree-sorted permutation (counting sort over clamped degree) ----
  const int bkt = (v < 63) ? v : 63;
  atomicAdd(&hist[bkt], 1);
  __syncthreads();
  if (t == 0) {
    int s = 0;
#pragma unroll 1
    for (int i = 0; i < 64; ++i) { const int h = hist[i]; hoff[i] = s; s += h; }
  }
  __syncthreads();
  const int pp = atomicAdd(&hoff[bkt], 1);
  perm[b * NPG + pp] = t;
}

// ---------------- Embedding gather (f32 -> bf16, unscaled) + fac init -----------
__global__ __launch_bounds__(256) void gather_k(
    const int* __restrict__ x_ids, const float* __restrict__ emb,
    u16* __restrict__ x0, float* __restrict__ fac)
{
  const int gid = blockIdx.x * 256 + threadIdx.x;  // NNODES*16 threads
  const int n = gid >> 4, c = gid & 15;
  const int id = x_ids[n];
  const float4 v0 = *(const float4*)(emb + (size_t)id * DF + c * 8);
  const float4 v1 = *(const float4*)(emb + (size_t)id * DF + c * 8 + 4);
  uint4 pk;
  pk.x = f2bf(v0.x) | (f2bf(v0.y) << 16);
  pk.y = f2bf(v0.z) | (f2bf(v0.w) << 16);
  pk.z = f2bf(v1.x) | (f2bf(v1.y) << 16);
  pk.w = f2bf(v1.z) | (f2bf(v1.w) << 16);
  *(uint4*)(x0 + (size_t)n * DF + c * 8) = pk;
  if (c == 0) fac[n] = 1.0f;
}

// ---- Weight convert into SWIZZLED fragment order -------------------------------
__global__ __launch_bounds__(64) void wcvt_k(
    const float* __restrict__ Wl1, const float* __restrict__ Wr1,
    const float* __restrict__ Wl2, const float* __restrict__ Wr2,
    const float* __restrict__ Wl3, const float* __restrict__ Wr3,
    u16* __restrict__ wF)
{
  const int f = blockIdx.x & 63, l = blockIdx.x >> 6;
  const int lane = threadIdx.x;
  const int ct = f >> 3, ks = f & 7;
  const int n = ct * 16 + (lane & 15);
  const int k0 = ks * 32 + (lane >> 4) * 8;
  const float* Wl = (l == 0) ? Wl1 : (l == 1) ? Wl2 : Wl3;
  const float* Wr = (l == 0) ? Wr1 : (l == 1) ? Wr2 : Wr3;
  u16 o[8];
#pragma unroll
  for (int j = 0; j < 8; ++j) {
    const int k = k0 + j;
    const float v = (k < 128) ? Wl[k * 128 + n] : Wr[(k - 128) * 128 + n];
    o[j] = (u16)f2bf(v);
  }
  uint4 pk;
  pk.x = (u32)o[0] | ((u32)o[1] << 16);
  pk.y = (u32)o[2] | ((u32)o[3] << 16);
  pk.z = (u32)o[4] | ((u32)o[5] << 16);
  pk.w = (u32)o[6] | ((u32)o[7] << 16);
  *(uint4*)(wF + (((size_t)l * 64 + f) * 64 + lane) * 8) = pk;
}

// ---- Aggregation v7: 8-group swizzle + scalar accum + fused readout ------------
__global__ __launch_bounds__(1024) void agg_k(
    const u16* __restrict__ xprev, const float* __restrict__ fac,
    const float* __restrict__ keep, const float* __restrict__ deg,
    const int* __restrict__ csr_src, const int* __restrict__ row_off,
    const int* __restrict__ row_cnt, const int* __restrict__ perm,
    u16* __restrict__ aggb, float* __restrict__ ro)
{
  __shared__ u32 xl[16384];          // 64 KB: 1024 rows x 16 dwords (32 bf16)
  __shared__ float keepL[NPG];       // 4 KB
  __shared__ float4 scr[256];        // 4 KB readout partials
  const int t = threadIdx.x;
  const int bi = blockIdx.x;         // 1024 = 256 graphs x 4 quarters
  const int g  = (bi & 7) + 8 * (bi >> 5);     // XCD swizzle
  const int qt = (bi >> 3) & 3;
  const int n  = g * NPG + t;
  // ---- stage (scaled, swizzled; group = 4*(r&1) + ((r>>1)&3) -> all 8) ----
  {
    const float fr = fac[n];
    const uint4* src = (const uint4*)(xprev + (size_t)n * DF + qt * 32);
    u32* dst = xl + t * 16;
    const int sw = ((t >> 1) & 3) << 2;
#pragma unroll
    for (int j = 0; j < 4; ++j) {
      const uint4 v = src[j];
      uint4 o;
      o.x = f2bf(bflo(v.x) * fr) | (f2bf(bfhi(v.x) * fr) << 16);
      o.y = f2bf(bflo(v.y) * fr) | (f2bf(bfhi(v.y) * fr) << 16);
      o.z = f2bf(bflo(v.z) * fr) | (f2bf(bfhi(v.z) * fr) << 16);
      o.w = f2bf(bflo(v.w) * fr) | (f2bf(bfhi(v.w) * fr) << 16);
      *(uint4*)(dst + ((j << 2) ^ sw)) = o;
    }
    if (ro) keepL[t] = keep[n];
  }
  const int m  = perm[n];            // node this thread aggregates
  const int nm = g * NPG + m;
  __syncthreads();
  // ---- gather-sum from LDS ----
  const int cnt = row_cnt[nm];
  const int* ep = csr_src + g * EPG + row_off[nm];
  float b[32];
#pragma unroll
  for (int j = 0; j < 32; ++j) b[j] = 0.0f;
  int e = 0;
  for (; e + 2 <= cnt; e += 2) {
    const int s0 = ep[e] & (NPG - 1), s1 = ep[e + 1] & (NPG - 1);
    const u32* r0 = xl + s0 * 16; const int w0 = ((s0 >> 1) & 3) << 2;
    const u32* r1 = xl + s1 * 16; const int w1 = ((s1 >> 1) & 3) << 2;
    const uint4 A0 = *(const uint4*)(r0 + (0  ^ w0));
    const uint4 A1 = *(const uint4*)(r0 + (4  ^ w0));
    const uint4 A2 = *(const uint4*)(r0 + (8  ^ w0));
    const uint4 A3 = *(const uint4*)(r0 + (12 ^ w0));
    const uint4 B0 = *(const uint4*)(r1 + (0  ^ w1));
    const uint4 B1 = *(const uint4*)(r1 + (4  ^ w1));
    const uint4 B2 = *(const uint4*)(r1 + (8  ^ w1));
    const uint4 B3 = *(const uint4*)(r1 + (12 ^ w1));
    acc8(b + 0, A0); acc8(b + 8, A1); acc8(b + 16, A2); acc8(b + 24, A3);
    acc8(b + 0, B0); acc8(b + 8, B1); acc8(b + 16, B2); acc8(b + 24, B3);
  }
  if (e < cnt) {
    const int s0 = ep[e] & (NPG - 1);
    const u32* r0 = xl + s0 * 16; const int w0 = ((s0 >> 1) & 3) << 2;
    const uint4 A0 = *(const uint4*)(r0 + (0  ^ w0));
    const uint4 A1 = *(const uint4*)(r0 + (4  ^ w0));
    const uint4 A2 = *(const uint4*)(r0 + (8  ^ w0));
    const uint4 A3 = *(const uint4*)(r0 + (12 ^ w0));
    acc8(b + 0, A0); acc8(b + 8, A1); acc8(b + 16, A2); acc8(b + 24, A3);
  }
  const float inv = 1.0f / fmaxf(deg[nm], 1.0f);
  uint4* op = (uint4*)(aggb + (size_t)nm * DF + qt * 32);
  op[0] = pack8(b + 0,  inv);
  op[1] = pack8(b + 8,  inv);
  op[2] = pack8(b + 16, inv);
  op[3] = pack8(b + 24, inv);
  // ---- fused readout of the PREVIOUS layer (staged tile = fac*x, masked) ----
  if (ro) {
    const int dw = t & 15, ck = t >> 4;          // dword col, 16-row chunk
    const float NEG = -__builtin_huge_valf();
    float mx0 = NEG, mx1 = NEG, sm0 = 0.0f, sm1 = 0.0f;
#pragma unroll
    for (int i = 0; i < 16; ++i) {
      const int r = ck * 16 + ((i + ck) & 15);   // stagger: 2-way banks, free
      const u32 u = xl[r * 16 + (dw ^ (((r >> 1) & 3) << 2))];
      if (keepL[r] > 0.5f) {
        const float lo = bflo(u), hi = bfhi(u);
        mx0 = fmaxf(mx0, lo); mx1 = fmaxf(mx1, hi);
        sm0 += lo; sm1 += hi;
      }
    }
    mx0 = fmaxf(mx0, __shfl_xor(mx0, 16, 64));
    mx1 = fmaxf(mx1, __shfl_xor(mx1, 16, 64));
    sm0 += __shfl_xor(sm0, 16, 64);
    sm1 += __shfl_xor(sm1, 16, 64);
    mx0 = fmaxf(mx0, __shfl_xor(mx0, 32, 64));
    mx1 = fmaxf(mx1, __shfl_xor(mx1, 32, 64));
    sm0 += __shfl_xor(sm0, 32, 64);
    sm1 += __shfl_xor(sm1, 32, 64);
    const int lane = t & 63, wv = t >> 6;
    if (lane < 16) scr[wv * 16 + dw] = make_float4(mx0, mx1, sm0, sm1);
    __syncthreads();
    if (t < 16) {
      float4 a = scr[t];
#pragma unroll 1
      for (int w = 1; w < 16; ++w) {
        const float4 c = scr[w * 16 + t];
        a.x = fmaxf(a.x, c.x); a.y = fmaxf(a.y, c.y);
        a.z += c.z; a.w += c.w;
      }
      float* o = ro + (size_t)g * 256;
      o[qt * 32 + 2 * t]           = a.x;
      o[qt * 32 + 2 * t + 1]       = a.y;
      o[128 + qt * 32 + 2 * t]     = a.z;
      o[128 + qt * 32 + 2 * t + 1] = a.w;
    }
  }
}

// ---- MFMA GEMM v6: weights in LDS (frees 128 VGPRs), barrier-free main loop ----
// R2 showed VGPR_Count=112 < 128 needed for reg-resident weights -> compiler
// re-loaded them from global every tile (the latency serializer). Stage the
// 64KB weight block in LDS once; ds_read_b128 fragments inside the MFMA loop
// (lane-contiguous 16B -> 8-way spread = b128 floor). Row prefetch stays.
__global__ __launch_bounds__(512) void gemm_nb_k(
    const u16* __restrict__ G, const u16* __restrict__ F,
    const float* __restrict__ fac,
    const u16* __restrict__ wF, const float* __restrict__ bl,
    const float* __restrict__ p, u16* __restrict__ H,
    float* __restrict__ score)
{
  __shared__ uint4 wL[4096];           // 64 KB: fragment (f,lane) -> uint4
  __shared__ float sc[256][2];
  const int t = threadIdx.x;
  const int bi = blockIdx.x;           // 1024 = 256 graphs x 4
  const int g   = (bi & 7) + 8 * (bi >> 5);
  const int tpg = (bi >> 3) & 3;
  const int n0  = g * NPG + tpg * 256;
  const int wv = t >> 6, lane = t & 63;
  const int rg = wv >> 1, ch = wv & 1;
  const int lr = lane & 15, quad = lane >> 4;

  // ---- stage layer weights into LDS (once per block) ----
  {
    const uint4* ws = (const uint4*)wF;
#pragma unroll
    for (int c = 0; c < 8; ++c) wL[t + c * 512] = ws[t + c * 512];
  }
  float4 bn4[4], pn4[4];
#pragma unroll
  for (int ct = 0; ct < 4; ++ct) {
    const int fb = ch * 64 + ct * 16 + quad * 4;
    bn4[ct] = *(const float4*)(bl + fb);
    pn4[ct] = *(const float4*)(p + fb);
  }

  const int rb0 = n0 + rg * 64 + lr;
  short8 agc[4], axc[4], agn[4], axn[4];
  float frc, frn = 0.0f;
#pragma unroll
  for (int ks = 0; ks < 4; ++ks) {
    agn[ks] = (short8)(short)0;
    axn[ks] = (short8)(short)0;
    agc[ks] = *(const short8*)(G + (size_t)rb0 * DF + ks * 32 + quad * 8);
    axc[ks] = *(const short8*)(F + (size_t)rb0 * DF + ks * 32 + quad * 8);
  }
  frc = fac[rb0];
  __syncthreads();                     // weights staged

  const short8* wLs = (const short8*)wL;   // fragment f at wLs[f*64+lane]
#pragma unroll
  for (int tl = 0; tl < 4; ++tl) {
    const int row = rb0 + tl * 16;
    if (tl < 3) {
      const int rown = row + 16;
#pragma unroll
      for (int ks = 0; ks < 4; ++ks) {
        agn[ks] = *(const short8*)(G + (size_t)rown * DF + ks * 32 + quad * 8);
        axn[ks] = *(const short8*)(F + (size_t)rown * DF + ks * 32 + quad * 8);
      }
      frn = fac[rown];
    }
    floatx4 aL[4], aR[4];
#pragma unroll
    for (int ct = 0; ct < 4; ++ct) {
      aL[ct] = (floatx4){0.f, 0.f, 0.f, 0.f};
      aR[ct] = (floatx4){0.f, 0.f, 0.f, 0.f};
    }
#pragma unroll
    for (int ks = 0; ks < 4; ++ks)
#pragma unroll
      for (int ct = 0; ct < 4; ++ct) {
        const int f = (ch * 4 + ct) * 8;
        const short8 bfa = wLs[(size_t)(f + ks) * 64 + lane];
        const short8 bfb = wLs[(size_t)(f + ks + 4) * 64 + lane];
        aL[ct] = __builtin_amdgcn_mfma_f32_16x16x32_bf16(bfa, agc[ks], aL[ct], 0, 0, 0);
        aR[ct] = __builtin_amdgcn_mfma_f32_16x16x32_bf16(bfb, axc[ks], aR[ct], 0, 0, 0);
      }
    float si = 0.0f;
#pragma unroll
    for (int ct = 0; ct < 4; ++ct) {
      float v0 = fmaxf(aL[ct][0] + frc * aR[ct][0] + bn4[ct].x, 0.0f);
      float v1 = fmaxf(aL[ct][1] + frc * aR[ct][1] + bn4[ct].y, 0.0f);
      float v2 = fmaxf(aL[ct][2] + frc * aR[ct][2] + bn4[ct].z, 0.0f);
      float v3 = fmaxf(aL[ct][3] + frc * aR[ct][3] + bn4[ct].w, 0.0f);
      si += v0 * pn4[ct].x + v1 * pn4[ct].y + v2 * pn4[ct].z + v3 * pn4[ct].w;
      uint2 st;
      st.x = f2bf(v0) | (f2bf(v1) << 16);
      st.y = f2bf(v2) | (f2bf(v3) << 16);
      *(uint2*)(H + (size_t)row * DF + ch * 64 + ct * 16 + quad * 4) = st;
    }
    si += __shfl_xor(si, 16, 64);
    si += __shfl_xor(si, 32, 64);
    if (lane < 16) sc[rg * 64 + tl * 16 + lr][ch] = si;
#pragma unroll
    for (int ks = 0; ks < 4; ++ks) { agc[ks] = agn[ks]; axc[ks] = axn[ks]; }
    frc = frn;
  }
  __syncthreads();   // sc complete across ch pair
  if (t < 256) score[n0 + t] = sc[t][0] + sc[t][1];
}

// ---- Per-graph top-k rank (exact argsort semantics) + edge-parallel next-deg ---
__global__ __launch_bounds__(1024) void rank_k(
    const float* __restrict__ score, const float* __restrict__ p,
    const int* __restrict__ ei,
    float* __restrict__ keep, float* __restrict__ fac,
    float* __restrict__ degN, int K, int next)
{
  __shared__ float s_lds[NPG];
  __shared__ float kfl[NPG];
  __shared__ float deg_l[NPG];
  const int b = blockIdx.x, t = threadIdx.x;
  float ssq = 0.0f;
  for (int d = 0; d < DF; ++d) ssq += p[d] * p[d];
  const float inv_pn = 1.0f / sqrtf(ssq);
  const float NEG = -__builtin_huge_valf();
  {
    const int n = b * NPG + t;
    s_lds[t] = (keep[n] > 0.5f) ? score[n] : NEG;
    deg_l[t] = 0.0f;
  }
  __syncthreads();
  const float si = s_lds[t];
  int rk = 0;
  for (int j = 0; j < NPG; ++j) {
    const float sj = s_lds[j];
    rk += (sj > si) || ((sj == si) && (j < t));
  }
  const bool kp = rk < K;
  const int n = b * NPG + t;
  keep[n] = kp ? 1.0f : 0.0f;
  kfl[t]  = kp ? 1.0f : 0.0f;
  fac[n]  = kp ? tanhf(si * inv_pn) : 0.0f;
  __syncthreads();
  if (next) {
    const int e0 = b * EPG;
    for (int e = t; e < EPG; e += 1024) {
      const int sl = ei[e0 + e] & (NPG - 1);
      const int dl = ei[NEDGE + e0 + e] & (NPG - 1);
      atomicAdd(&deg_l[dl], kfl[sl]);
    }
    __syncthreads();
    degN[n] = deg_l[t];
  }
}

// ---- Parallel masked readout (layer 3 only): 8 blocks/graph, partial format ----
__global__ __launch_bounds__(256) void readout_k(
    const u16* __restrict__ xn, const float* __restrict__ fac,
    const float* __restrict__ keep, float* __restrict__ xlp)
{
  __shared__ float mxA[256], mxB[256], smA[256], smB[256];
  const int blk = blockIdx.x, b = blk >> 3, pr = blk & 7, t = threadIdx.x;
  const int d = t & 63, rq = t >> 6;
  const float NEG = -__builtin_huge_valf();
  float mx0 = NEG, mx1 = NEG, sm0 = 0.0f, sm1 = 0.0f;
  for (int j = 0; j < 32; ++j) {
    const int n = b * NPG + pr * 128 + rq + j * 4;
    const float kf = keep[n];
    const float f  = fac[n];
    const u32 u = *(const u32*)(xn + (size_t)n * DF + d * 2);
    const float v0 = bflo(u) * f, v1 = bfhi(u) * f;
    if (kf > 0.5f) {
      mx0 = fmaxf(mx0, v0); mx1 = fmaxf(mx1, v1);
      sm0 += v0; sm1 += v1;
    }
  }
  mxA[t] = mx0; mxB[t] = mx1; smA[t] = sm0; smB[t] = sm1;
  __syncthreads();
  if (t < 64) {
    float m0 = mxA[t], m1 = mxB[t], s0 = smA[t], s1 = smB[t];
#pragma unroll
    for (int qq = 1; qq < 4; ++qq) {
      m0 = fmaxf(m0, mxA[qq * 64 + t]); m1 = fmaxf(m1, mxB[qq * 64 + t]);
      s0 += smA[qq * 64 + t];           s1 += smB[qq * 64 + t];
    }
    float* o = xlp + (size_t)blk * 256;
    o[2 * t]           = m0;
    o[2 * t + 1]       = m1;
    o[128 + 2 * t]     = s0;
    o[128 + 2 * t + 1] = s1;
  }
}

// ---------------- Final MLP head, one block per graph ----------------
__global__ __launch_bounds__(256) void mlp_k(
    const float* __restrict__ xlpF, const float* __restrict__ xlp2,
    const float* __restrict__ W1, const float* __restrict__ b1,
    const float* __restrict__ W2, const float* __restrict__ b2,
    const float* __restrict__ W3, const float* __restrict__ b3,
    float* __restrict__ out)
{
  __shared__ float h0[256];
  __shared__ float h1[128];
  __shared__ float h2[64];
  const int b = blockIdx.x, t = threadIdx.x;
  const float invK[3] = {1.0f / (float)K1, 1.0f / (float)K2, 1.0f / (float)K3};
  const float* f0 = xlpF + (size_t)b * 256;
  const float* f1 = xlpF + (size_t)(NB + b) * 256;
  float v;
  if (t < 128) v = f0[t] + f1[t];
  else         v = f0[t] * invK[0] + f1[t] * invK[1];
  {
    const float* base = xlp2 + (size_t)b * 8 * 256;
    if (t < 128) {
      float m = base[t];
#pragma unroll
      for (int pr = 1; pr < 8; ++pr) m = fmaxf(m, base[pr * 256 + t]);
      v += m;
    } else {
      float s = 0.0f;
#pragma unroll
      for (int pr = 0; pr < 8; ++pr) s += base[pr * 256 + t];
      v += s * invK[2];
    }
  }
  h0[t] = v;
  __syncthreads();
  if (t < 128) {
    float a = b1[t];
    for (int k = 0; k < 256; ++k) a += h0[k] * W1[k * 128 + t];
    h1[t] = fmaxf(a, 0.0f);
  }
  __syncthreads();
  if (t < 64) {
    float a = b2[t];
    for (int k = 0; k < 128; ++k) a += h1[k] * W2[k * 64 + t];
    h2[t] = fmaxf(a, 0.0f);
  }
  __syncthreads();
  if (t < 64) {
    float vv = h2[t] * W3[t];
#pragma unroll
    for (int off = 32; off > 0; off >>= 1) vv += __shfl_xor(vv, off, 64);
    if (t == 0) out[b] = 1.0f / (1.0f + expf(-(vv + b3[0])));
  }
}

extern "C" void kernel_launch(void* const* d_in, const int* in_sizes, int n_in,
                              void* d_out, int out_size, void* d_ws, size_t ws_size,
                              hipStream_t stream)
{
  const int*   x_ids = (const int*)d_in[0];
  const int*   ei    = (const int*)d_in[1];
  const float* emb   = (const float*)d_in[3];
  const float* Wl[3]  = {(const float*)d_in[4],  (const float*)d_in[8],  (const float*)d_in[12]};
  const float* blv[3] = {(const float*)d_in[5],  (const float*)d_in[9],  (const float*)d_in[13]};
  const float* Wr[3]  = {(const float*)d_in[6],  (const float*)d_in[10], (const float*)d_in[14]};
  const float* pv[3]  = {(const float*)d_in[7],  (const float*)d_in[11], (const float*)d_in[15]};
  const float* W1 = (const float*)d_in[16]; const float* b1 = (const float*)d_in[17];
  const float* W2 = (const float*)d_in[18]; const float* b2 = (const float*)d_in[19];
  const float* W3 = (const float*)d_in[20]; const float* b3 = (const float*)d_in[21];

  char* ws = (char*)d_ws;
  size_t off = 0;
  auto alloc = [&](size_t bytes) -> void* {
    void* ptr = ws + off; off += (bytes + 255) & ~(size_t)255; return ptr;
  };
  u16*   xA    = (u16*)  alloc((size_t)NNODES * DF * 2);   // feature ping
  u16*   xB    = (u16*)  alloc((size_t)NNODES * DF * 2);   // agg buffer
  float* score = (float*)alloc((size_t)NNODES * 4);
  float* keep  = (float*)alloc((size_t)NNODES * 4);
  float* fac   = (float*)alloc((size_t)NNODES * 4);
  float* degf  = (float*)alloc((size_t)NNODES * 4);
  int*   csr   = (int*)  alloc((size_t)NEDGE * 4);
  int*   roff  = (int*)  alloc((size_t)NNODES * 4);
  int*   rcnt  = (int*)  alloc((size_t)NNODES * 4);
  int*   perm  = (int*)  alloc((size_t)NNODES * 4);
  u16*   wF    = (u16*)  alloc((size_t)3 * 64 * 64 * 8 * 2);
  float* xlpF  = (float*)alloc((size_t)2 * NB * 256 * 4);   // fused readout l0,l1
  float* xlp2  = (float*)alloc((size_t)NB * 8 * 256 * 4);   // partial readout l2
  const size_t off_base = off;
  u16*   xC    = (u16*)  alloc((size_t)NNODES * DF * 2);   // feature pong (v5 path)
  const bool use3 = (off <= ws_size);
  (void)in_sizes; (void)n_in; (void)out_size;
  if (off_base > ws_size) return;   // graceful fail instead of OOB fault
  if (!use3) return;                // v6 requires the 3rd buffer (has fit so far)

  wcvt_k<<<192, 64, 0, stream>>>(Wl[0], Wr[0], Wl[1], Wr[1], Wl[2], Wr[2], wF);
  build_csr_k<<<NB, 1024, 0, stream>>>(ei, csr, roff, rcnt, degf, keep, perm);
  gather_k<<<NNODES * 16 / 256, 256, 0, stream>>>(x_ids, emb, xA, fac);
  const int Ks[3] = {K1, K2, K3};
  u16* F = xA;
  u16* H = xC;
  for (int l = 0; l < 3; ++l) {
    float* ro = (l == 0) ? nullptr : xlpF + (size_t)(l - 1) * NB * 256;
    agg_k<<<1024, 1024, 0, stream>>>(F, fac, keep, degf, csr, roff, rcnt, perm,
                                     xB, ro);
    gemm_nb_k<<<1024, 512, 0, stream>>>(xB, F, fac, wF + (size_t)l * 32768,
                                        blv[l], pv[l], H, score);
    rank_k<<<NB, 1024, 0, stream>>>(score, pv[l], ei, keep, fac, degf,
                                    Ks[l], l < 2 ? 1 : 0);
    u16* tmp = F; F = H; H = tmp;   // xn (in F now) is next layer's features
  }
  readout_k<<<NB * 8, 256, 0, stream>>>(F, fac, keep, xlp2);   // layer 2
  mlp_k<<<NB, 256, 0, stream>>>(xlpF, xlp2, W1, b1, W2, b2, W3, b3, (float*)d_out);
}